// Round 9
// baseline (251.408 us; speedup 1.0000x reference)
//
#include <hip/hip_runtime.h>
#include <hip/hip_fp16.h>
#include <math.h>

#define D_MODEL 768
#define EMB 33
#define ORDER 64
#define SEQ 8192
#define BATCH 2
#define M 8192      // half-size complex FFT length (N = 16384 real)

#define PI_F 3.14159265358979323846f

// padded LDS index in COMPLEX units: +1 per 16, +1 per 128
#define IDX(a) ((a) + ((a) >> 4) + ((a) >> 7))
#define LDS_SZ 8768      // complex slots; 8768*8B = 70,144 B -> 2 blocks/CU

__device__ __forceinline__ int rev13(int x) { return (int)(__brev((unsigned)x) >> 19); }

// twiddle constants (angle pi*k/8): C8=cos, S8n=-sin (forward), S8p=+sin (inverse)
__device__ __constant__ float C8[8] = {
    1.f, 0.9238795325f, 0.7071067812f, 0.3826834324f,
    0.f, -0.3826834324f, -0.7071067812f, -0.9238795325f };
__device__ __constant__ float S8n[8] = {
    0.f, -0.3826834324f, -0.7071067812f, -0.9238795325f,
    -1.f, -0.9238795325f, -0.7071067812f, -0.3826834324f };
__device__ __constant__ float S8p[8] = {
    0.f, 0.3826834324f, 0.7071067812f, 0.9238795325f,
    1.f, 0.9238795325f, 0.7071067812f, 0.3826834324f };

// ---------------- MLP: h3T[o][l] = sin-MLP(z[l])[o], register-tiled ----------
__global__ __launch_bounds__(256) void mlp_kernel(
    const float* __restrict__ z, const float* __restrict__ freq,
    const float* __restrict__ W1, const float* __restrict__ b1,
    const float* __restrict__ W2, const float* __restrict__ b2,
    const float* __restrict__ W3, const float* __restrict__ b3,
    float* __restrict__ h3T)
{
    __shared__ float zt[33 * 72];    // zt[e][l], rows of 72 (288B, 16B-aligned)
    __shared__ float h1[64 * 72];    // h[o][l]
    __shared__ float h2[64 * 72];
    __shared__ float Wb[64 * 68];    // W[e][o], rows of 68 (272B, 16B-aligned)
    __shared__ float sfr[64], sb[64];
    int t = threadIdx.x;
    int l0 = blockIdx.x * 64;

    for (int i = t; i < 64 * 33; i += 256) {
        int l = i / 33, e = i - l * 33;
        zt[e * 72 + l] = z[(size_t)(l0 + l) * 33 + e];
    }
    for (int i = t; i < 64 * 33; i += 256) {
        int o = i / 33, e = i - o * 33;
        Wb[e * 68 + o] = W1[i];
    }
    if (t < 64) { sfr[t] = freq[t]; sb[t] = b1[t]; }
    __syncthreads();

    int lx = t & 15, oy = t >> 4;           // 16 lx * 4l = 64 l; 16 oy * 4o = 64 o
    float fr4[4], bi4[4], acc[4][4];
#pragma unroll
    for (int i = 0; i < 4; ++i) { fr4[i] = sfr[4 * oy + i]; bi4[i] = sb[4 * oy + i]; }
#pragma unroll
    for (int c = 0; c < 4; ++c)
#pragma unroll
        for (int i = 0; i < 4; ++i) acc[c][i] = bi4[i];
    for (int e = 0; e < 33; ++e) {
        float4 hv = *(const float4*)&zt[e * 72 + 4 * lx];
        float4 wv = *(const float4*)&Wb[e * 68 + 4 * oy];
        float h[4] = {hv.x, hv.y, hv.z, hv.w}, w[4] = {wv.x, wv.y, wv.z, wv.w};
#pragma unroll
        for (int c = 0; c < 4; ++c)
#pragma unroll
            for (int i = 0; i < 4; ++i) acc[c][i] = fmaf(h[c], w[i], acc[c][i]);
    }
#pragma unroll
    for (int i = 0; i < 4; ++i) {
        float4 v = make_float4(__sinf(fr4[i] * acc[0][i]), __sinf(fr4[i] * acc[1][i]),
                               __sinf(fr4[i] * acc[2][i]), __sinf(fr4[i] * acc[3][i]));
        *(float4*)&h1[(4 * oy + i) * 72 + 4 * lx] = v;
    }
    __syncthreads();

    for (int i = t; i < 4096; i += 256) {    // W2[o][q] -> Wb[q][o]
        int o = i >> 6, q = i & 63;
        Wb[q * 68 + o] = W2[i];
    }
    if (t < 64) sb[t] = b2[t];
    __syncthreads();
#pragma unroll
    for (int i = 0; i < 4; ++i) bi4[i] = sb[4 * oy + i];
#pragma unroll
    for (int c = 0; c < 4; ++c)
#pragma unroll
        for (int i = 0; i < 4; ++i) acc[c][i] = bi4[i];
    for (int q = 0; q < 64; ++q) {
        float4 hv = *(const float4*)&h1[q * 72 + 4 * lx];
        float4 wv = *(const float4*)&Wb[q * 68 + 4 * oy];
        float h[4] = {hv.x, hv.y, hv.z, hv.w}, w[4] = {wv.x, wv.y, wv.z, wv.w};
#pragma unroll
        for (int c = 0; c < 4; ++c)
#pragma unroll
            for (int i = 0; i < 4; ++i) acc[c][i] = fmaf(h[c], w[i], acc[c][i]);
    }
#pragma unroll
    for (int i = 0; i < 4; ++i) {
        float4 v = make_float4(__sinf(fr4[i] * acc[0][i]), __sinf(fr4[i] * acc[1][i]),
                               __sinf(fr4[i] * acc[2][i]), __sinf(fr4[i] * acc[3][i]));
        *(float4*)&h2[(4 * oy + i) * 72 + 4 * lx] = v;
    }
    __syncthreads();

    for (int i = t; i < 4096; i += 256) {    // W3[o][q] -> Wb[q][o]
        int o = i >> 6, q = i & 63;
        Wb[q * 68 + o] = W3[i];
    }
    if (t < 64) sb[t] = b3[t];
    __syncthreads();
#pragma unroll
    for (int i = 0; i < 4; ++i) bi4[i] = sb[4 * oy + i];
#pragma unroll
    for (int c = 0; c < 4; ++c)
#pragma unroll
        for (int i = 0; i < 4; ++i) acc[c][i] = bi4[i];
    for (int q = 0; q < 64; ++q) {
        float4 hv = *(const float4*)&h2[q * 72 + 4 * lx];
        float4 wv = *(const float4*)&Wb[q * 68 + 4 * oy];
        float h[4] = {hv.x, hv.y, hv.z, hv.w}, w[4] = {wv.x, wv.y, wv.z, wv.w};
#pragma unroll
        for (int c = 0; c < 4; ++c)
#pragma unroll
            for (int i = 0; i < 4; ++i) acc[c][i] = fmaf(h[c], w[i], acc[c][i]);
    }
#pragma unroll
    for (int i = 0; i < 4; ++i) {
        float4 v = make_float4(__sinf(fr4[i] * acc[0][i]), __sinf(fr4[i] * acc[1][i]),
                               __sinf(fr4[i] * acc[2][i]), __sinf(fr4[i] * acc[3][i]));
        *(float4*)&h3T[(size_t)(4 * oy + i) * SEQ + l0 + 4 * lx] = v;
    }
}

// ------- filter: k[d][l] = (h3[l]·Wout[d]) * exp(-t[l]*|delta[d]|), tiled -------
__global__ __launch_bounds__(256) void filt_kernel(
    const float* __restrict__ h3T, const float* __restrict__ Wout,
    const float* __restrict__ tvec, const float* __restrict__ deltas,
    float* __restrict__ kout)
{
    __shared__ float ht[64 * 132];   // ht[kk][l], rows 132 (528B, 16B-aligned)
    __shared__ float wt[64 * 68];    // wt[kk][dd], rows 68
    int t = threadIdx.x;
    int l0 = blockIdx.x * 128, d0 = blockIdx.y * 64;

    for (int i = t; i < 64 * 128; i += 256) {
        int o = i >> 7, l = i & 127;
        ht[o * 132 + l] = h3T[(size_t)o * SEQ + l0 + l];
    }
    for (int i = t; i < 4096; i += 256) {    // Wout[d][kk] -> wt[kk][dd]
        int dd = i >> 6, kk = i & 63;
        wt[kk * 68 + dd] = Wout[(size_t)(d0 + dd) * 64 + kk];
    }
    __syncthreads();

    int lx = t & 31, dy = t >> 5;            // 32 lx * 4l = 128; 8 dy * 8d = 64
    float acc[4][8];
#pragma unroll
    for (int c = 0; c < 4; ++c)
#pragma unroll
        for (int i = 0; i < 8; ++i) acc[c][i] = 0.f;
    for (int kk = 0; kk < 64; ++kk) {
        float4 hv = *(const float4*)&ht[kk * 132 + 4 * lx];
        float4 w0 = *(const float4*)&wt[kk * 68 + 8 * dy];
        float4 w1 = *(const float4*)&wt[kk * 68 + 8 * dy + 4];
        float h[4] = {hv.x, hv.y, hv.z, hv.w};
        float w[8] = {w0.x, w0.y, w0.z, w0.w, w1.x, w1.y, w1.z, w1.w};
#pragma unroll
        for (int c = 0; c < 4; ++c)
#pragma unroll
            for (int i = 0; i < 8; ++i) acc[c][i] = fmaf(h[c], w[i], acc[c][i]);
    }

    float4 tl4 = *(const float4*)&tvec[l0 + 4 * lx];
    float tl[4] = {tl4.x, tl4.y, tl4.z, tl4.w};
    float del[8];
#pragma unroll
    for (int i = 0; i < 8; ++i) del[i] = fabsf(deltas[d0 + 8 * dy + i]);
#pragma unroll
    for (int i = 0; i < 8; ++i) {
        int d = d0 + 8 * dy + i;
        float4 v = make_float4(acc[0][i] * __expf(-tl[0] * del[i]),
                               acc[1][i] * __expf(-tl[1] * del[i]),
                               acc[2][i] * __expf(-tl[2] * del[i]),
                               acc[3][i] * __expf(-tl[3] * del[i]));
        *(float4*)&kout[(size_t)d * SEQ + l0 + 4 * lx] = v;
    }
}

// ======== radix-16 LDS passes: 4 stages per pass, 16 strided elems/thread =======
// fwd16<H>: DIF stages (H, H/2, H/4, H/8), stride H8=H/8, one group per thread.
// Leading stage twiddle = T1*exp(-i*pi*m/8) inline; then two radix-8 bodies
// (verbatim fwd8 stage code) with base twiddle T1^2.
template<int H>
__device__ __forceinline__ void fwd16(float2* A, int t)
{
    constexpr int H8 = H / 8;
    int j = t & (H8 - 1);
    int i = ((t & ~(H8 - 1)) << 4) | j;
    float c1, s1;
    __sincosf((-PI_F / (float)H) * (float)j, &s1, &c1);      // T1 = exp(-i*pi*j/H)
    float xr[16], xi[16];
#pragma unroll
    for (int m = 0; m < 16; ++m) {
        float2 v = A[IDX(i + m * H8)];
        xr[m] = v.x; xi[m] = v.y;
    }
#pragma unroll
    for (int m = 0; m < 8; ++m) {                            // stage half=H
        float tc = c1 * C8[m] - s1 * S8n[m];
        float ts = c1 * S8n[m] + s1 * C8[m];
        float ur = xr[m] + xr[m + 8], ui = xi[m] + xi[m + 8];
        float dr = xr[m] - xr[m + 8], di = xi[m] - xi[m + 8];
        xr[m] = ur; xi[m] = ui;
        xr[m + 8] = dr * tc - di * ts;
        xi[m + 8] = dr * ts + di * tc;
    }
    float cA = c1 * c1 - s1 * s1, sA = 2.f * c1 * s1;        // T1^2
    float cB = cA * cA - sA * sA, sB = 2.f * cA * sA;        // T1^4
    float cC = cB * cB - sB * sB, sC = 2.f * cB * sB;        // T1^8
    const float r = 0.70710678118f;
    float twc[4], tws[4];                                     // T1^2 * W8^m
    twc[0] = cA;            tws[0] = sA;
    twc[1] = r * (cA + sA); tws[1] = r * (sA - cA);
    twc[2] = sA;            tws[2] = -cA;
    twc[3] = r * (sA - cA); tws[3] = -r * (cA + sA);
#pragma unroll
    for (int hb = 0; hb < 16; hb += 8) {
#pragma unroll
        for (int m = 0; m < 4; ++m) {                         // stage half=H/2
            int a = hb + m, b = a + 4;
            float ur = xr[a] + xr[b], ui = xi[a] + xi[b];
            float dr = xr[a] - xr[b], di = xi[a] - xi[b];
            xr[a] = ur; xi[a] = ui;
            xr[b] = dr * twc[m] - di * tws[m];
            xi[b] = dr * tws[m] + di * twc[m];
        }
#pragma unroll
        for (int base = 0; base < 8; base += 4)               // stage half=H/4
#pragma unroll
            for (int mm = 0; mm < 2; ++mm) {
                int a = hb + base + mm, b = a + 2;
                float ur = xr[a] + xr[b], ui = xi[a] + xi[b];
                float dr = xr[a] - xr[b], di = xi[a] - xi[b];
                xr[a] = ur; xi[a] = ui;
                if (mm == 0) { xr[b] = dr * cB - di * sB; xi[b] = dr * sB + di * cB; }
                else         { xr[b] = dr * sB + di * cB; xi[b] = di * sB - dr * cB; }  // *(T1^4)*(-i)
            }
#pragma unroll
        for (int m = 0; m < 8; m += 2) {                      // stage half=H/8
            int a = hb + m;
            float ur = xr[a] + xr[a + 1], ui = xi[a] + xi[a + 1];
            float dr = xr[a] - xr[a + 1], di = xi[a] - xi[a + 1];
            xr[a] = ur; xi[a] = ui;
            xr[a + 1] = dr * cC - di * sC; xi[a + 1] = dr * sC + di * cC;
        }
    }
#pragma unroll
    for (int m = 0; m < 16; ++m) A[IDX(i + m * H8)] = make_float2(xr[m], xi[m]);
}

// inv16<H>: DIT stages (H, 2H, 4H, 8H), stride H. Two radix-8 bodies (verbatim
// inv8 stage code, base T = T8^2) then final half=8H stage with T8*exp(i*pi*m/8).
template<int H>
__device__ __forceinline__ void inv16(float2* A, int t)
{
    int j = t & (H - 1);
    int i = ((t & ~(H - 1)) << 4) | j;
    float c8, s8;
    __sincosf((PI_F / (float)(8 * H)) * (float)j, &s8, &c8); // T8 = exp(i*pi*j/(8H))
    float c  = c8 * c8 - s8 * s8,  s  = 2.f * c8 * s8;       // T  = T8^2
    float c2 = c * c - s * s,      s2 = 2.f * c * s;         // T^2
    float c4 = c2 * c2 - s2 * s2,  s4 = 2.f * c2 * s2;       // T^4
    float xr[16], xi[16];
#pragma unroll
    for (int m = 0; m < 16; ++m) {
        float2 v = A[IDX(i + m * H)];
        xr[m] = v.x; xi[m] = v.y;
    }
    const float r = 0.70710678118f;
    float t3c[4], t3s[4];                                     // T * exp(i*pi*m/4)
    t3c[0] = c;            t3s[0] = s;
    t3c[1] = r * (c - s);  t3s[1] = r * (c + s);
    t3c[2] = -s;           t3s[2] = c;
    t3c[3] = -r * (c + s); t3s[3] = r * (c - s);
#pragma unroll
    for (int hb = 0; hb < 16; hb += 8) {
#pragma unroll
        for (int m = 0; m < 8; m += 2) {                      // stage half=H
            int a = hb + m;
            float tr = xr[a + 1] * c4 - xi[a + 1] * s4;
            float ti = xr[a + 1] * s4 + xi[a + 1] * c4;
            xr[a + 1] = xr[a] - tr; xi[a + 1] = xi[a] - ti;
            xr[a]     = xr[a] + tr; xi[a]     = xi[a] + ti;
        }
#pragma unroll
        for (int base = 0; base < 8; base += 4)               // stage half=2H
#pragma unroll
            for (int mm = 0; mm < 2; ++mm) {
                int a = hb + base + mm, b = a + 2;
                float tr, ti;
                if (mm == 0) { tr = xr[b] * c2 - xi[b] * s2; ti = xr[b] * s2 + xi[b] * c2; }
                else         { tr = -(xr[b] * s2 + xi[b] * c2); ti = xr[b] * c2 - xi[b] * s2; }
                xr[b] = xr[a] - tr; xi[b] = xi[a] - ti;
                xr[a] = xr[a] + tr; xi[a] = xi[a] + ti;
            }
#pragma unroll
        for (int m = 0; m < 4; ++m) {                         // stage half=4H
            int a = hb + m, b = a + 4;
            float tr = xr[b] * t3c[m] - xi[b] * t3s[m];
            float ti = xr[b] * t3s[m] + xi[b] * t3c[m];
            xr[b] = xr[a] - tr; xi[b] = xi[a] - ti;
            xr[a] = xr[a] + tr; xi[a] = xi[a] + ti;
        }
    }
#pragma unroll
    for (int m = 0; m < 8; ++m) {                             // stage half=8H
        float tc = c8 * C8[m] - s8 * S8p[m];
        float ts = c8 * S8p[m] + s8 * C8[m];
        float tr = xr[m + 8] * tc - xi[m + 8] * ts;
        float ti = xr[m + 8] * ts + xi[m + 8] * tc;
        xr[m + 8] = xr[m] - tr; xi[m + 8] = xi[m] - ti;
        xr[m]     = xr[m] + tr; xi[m]     = xi[m] + ti;
    }
#pragma unroll
    for (int m = 0; m < 16; ++m) A[IDX(i + m * H)] = make_float2(xr[m], xi[m]);
}

// ------- forward FFT body (after load-fused half=4096): 2 LDS passes + tail ------
// Stage sequence: [load] 4096 | 2048,1024,512,256 | 128,64,32,16 | tail 8,4,2,1
__device__ __forceinline__ void fft_fwd(float2* A, int t)
{
    fwd16<2048>(A, t); __syncthreads();
    fwd16<128>(A, t);  __syncthreads();
    {   // register tail: halves 8,4,2,1 on 16 consecutive elements (R3-proven)
        int pb = IDX(16 * t);
        float fr[16], fi[16];
#pragma unroll
        for (int e = 0; e < 16; ++e) { float2 v = A[pb + e]; fr[e] = v.x; fi[e] = v.y; }
#pragma unroll
        for (int k = 0; k < 8; ++k) {                         // half=8
            float cs = C8[k], sn = S8n[k];
            float arr = fr[k], aii = fi[k], brr = fr[k + 8], bii = fi[k + 8];
            fr[k] = arr + brr; fi[k] = aii + bii;
            float dr = arr - brr, di = aii - bii;
            fr[k + 8] = dr * cs - di * sn; fi[k + 8] = dr * sn + di * cs;
        }
#pragma unroll
        for (int b0 = 0; b0 < 16; b0 += 8)                    // half=4
#pragma unroll
            for (int k = 0; k < 4; ++k) {
                float cs = C8[2 * k], sn = S8n[2 * k];
                int i0 = b0 + k, i1 = i0 + 4;
                float arr = fr[i0], aii = fi[i0], brr = fr[i1], bii = fi[i1];
                fr[i0] = arr + brr; fi[i0] = aii + bii;
                float dr = arr - brr, di = aii - bii;
                fr[i1] = dr * cs - di * sn; fi[i1] = dr * sn + di * cs;
            }
#pragma unroll
        for (int b0 = 0; b0 < 16; b0 += 4)                    // half=2
#pragma unroll
            for (int k = 0; k < 2; ++k) {
                float cs = C8[4 * k], sn = S8n[4 * k];
                int i0 = b0 + k, i1 = i0 + 2;
                float arr = fr[i0], aii = fi[i0], brr = fr[i1], bii = fi[i1];
                fr[i0] = arr + brr; fi[i0] = aii + bii;
                float dr = arr - brr, di = aii - bii;
                fr[i1] = dr * cs - di * sn; fi[i1] = dr * sn + di * cs;
            }
#pragma unroll
        for (int b0 = 0; b0 < 16; b0 += 2) {                  // half=1
            float arr = fr[b0], aii = fi[b0], brr = fr[b0 + 1], bii = fi[b0 + 1];
            fr[b0] = arr + brr; fi[b0] = aii + bii;
            fr[b0 + 1] = arr - brr; fi[b0 + 1] = aii - bii;
        }
#pragma unroll
        for (int e = 0; e < 16; ++e) A[pb + e] = make_float2(fr[e], fi[e]);
        __syncthreads();
    }
}

// ------- inverse FFT body (ends before store-fused half=4096): head + 2 passes ---
// Stage sequence: head 1,2,4,8 | 16,32,64,128 | 256,512,1024,2048 | [store] 4096
__device__ __forceinline__ void fft_inv(float2* A, int t)
{
    {   // register head: halves 1,2,4,8 on 16 consecutive elements (R3-proven)
        int pb = IDX(16 * t);
        float fr[16], fi[16];
#pragma unroll
        for (int e = 0; e < 16; ++e) { float2 v = A[pb + e]; fr[e] = v.x; fi[e] = v.y; }
#pragma unroll
        for (int b0 = 0; b0 < 16; b0 += 2) {                  // half=1
            float arr = fr[b0], aii = fi[b0], brr = fr[b0 + 1], bii = fi[b0 + 1];
            fr[b0] = arr + brr; fi[b0] = aii + bii;
            fr[b0 + 1] = arr - brr; fi[b0 + 1] = aii - bii;
        }
#pragma unroll
        for (int b0 = 0; b0 < 16; b0 += 4)                    // half=2
#pragma unroll
            for (int k = 0; k < 2; ++k) {
                float cs = C8[4 * k], sn = S8p[4 * k];
                int i0 = b0 + k, i1 = i0 + 2;
                float arr = fr[i0], aii = fi[i0], brr = fr[i1], bii = fi[i1];
                float tr = brr * cs - bii * sn, ti = brr * sn + bii * cs;
                fr[i0] = arr + tr; fi[i0] = aii + ti;
                fr[i1] = arr - tr; fi[i1] = aii - ti;
            }
#pragma unroll
        for (int b0 = 0; b0 < 16; b0 += 8)                    // half=4
#pragma unroll
            for (int k = 0; k < 4; ++k) {
                float cs = C8[2 * k], sn = S8p[2 * k];
                int i0 = b0 + k, i1 = i0 + 4;
                float arr = fr[i0], aii = fi[i0], brr = fr[i1], bii = fi[i1];
                float tr = brr * cs - bii * sn, ti = brr * sn + bii * cs;
                fr[i0] = arr + tr; fi[i0] = aii + ti;
                fr[i1] = arr - tr; fi[i1] = aii - ti;
            }
#pragma unroll
        for (int k = 0; k < 8; ++k) {                         // half=8
            float cs = C8[k], sn = S8p[k];
            float arr = fr[k], aii = fi[k], brr = fr[k + 8], bii = fi[k + 8];
            float tr = brr * cs - bii * sn, ti = brr * sn + bii * cs;
            fr[k] = arr + tr; fi[k] = aii + ti;
            fr[k + 8] = arr - tr; fi[k + 8] = aii - ti;
        }
#pragma unroll
        for (int e = 0; e < 16; ++e) A[pb + e] = make_float2(fr[e], fi[e]);
        __syncthreads();
    }
    inv16<16>(A, t);  __syncthreads();
    inv16<256>(A, t); __syncthreads();
}

// ---------------- kf: K_f[d] = rfft(k_d, 16384), fp16-packed into d_out rows ----
__global__ __launch_bounds__(512, 2) void kf_kernel(float* outk)
{
    __shared__ float2 A[LDS_SZ];
    int t = threadIdx.x, d = blockIdx.x;
    const float* kp = outk + (size_t)d * SEQ;
    {   // load + fused half=4096 (upper=0); independent per-idx rotations, full unroll
        float c0, s0;
        __sincosf((-PI_F / 4096.0f) * (float)t, &s0, &c0);
#pragma unroll
        for (int idx = 0; idx < 8; ++idx) {
            int n = t + (idx << 9);
            float2 v = ((const float2*)kp)[n];
            float cc = c0 * C8[idx] - s0 * S8n[idx];   // T0 * exp(-i*pi*idx/8)
            float ss = c0 * S8n[idx] + s0 * C8[idx];
            A[IDX(n)] = v;
            A[IDX(n + 4096)] = make_float2(v.x * cc - v.y * ss, v.x * ss + v.y * cc);
        }
    }
    __syncthreads();
    fft_fwd(A, t);

    __half2* P0 = (__half2*)(outk + (size_t)d * SEQ);
    __half2* P1 = (__half2*)(outk + (size_t)(D_MODEL + d) * SEQ);
    float cs, sn;
    __sincosf(-PI_F * (float)t * (1.0f / 8192.0f), &sn, &cs);
    const float cRo = 0.9807852804f, sRo = -0.1950903220f;   // exp(-i*pi/16), step 512
    for (int j = t; j <= 4096; j += 512) {
        int jm = (M - j) & (M - 1);
        int p0 = rev13(j), p1 = rev13(jm);
        float2 z1 = A[IDX(p0)], z2 = A[IDX(p1)];
        float Ar_ = 0.5f * (z1.x + z2.x), Ai_ = 0.5f * (z1.y - z2.y);
        float Br_ = 0.5f * (z1.y + z2.y), Bi_ = 0.5f * (z2.x - z1.x);
        float wbr = cs * Br_ - sn * Bi_, wbi = cs * Bi_ + sn * Br_;
        float K1r = Ar_ + wbr, K1i = Ai_ + wbi;
        float K2r = Ar_ - wbr, K2i = -(Ai_ - wbi);
        if (j == 0) {
            __half2 v = __floats2half2_rn(K1r, K2r);
            P0[0] = v; P1[0] = v;
        } else {
            __half2 v1 = __floats2half2_rn(K1r, K1i);
            P0[j] = v1; P1[j] = v1;
            if (j != 4096) {
                __half2 v2 = __floats2half2_rn(K2r, K2i);
                P0[M - j] = v2; P1[M - j] = v2;
            }
        }
        float cn = cs * cRo - sn * sRo; sn = sn * cRo + cs * sRo; cs = cn;
    }
}

// ---------------- conv: block (d,b): y = irfft(rfft(x)*(K + bias_d))[:8192] ------
// bias fold: y + x*bias_d == irfft(U_f * (K_f + bias_d))[:8192].
__global__ __launch_bounds__(512, 2) void conv_kernel(
    const float* __restrict__ x, const float* __restrict__ bias,
    float* outk)
{
    __shared__ float2 A[LDS_SZ];
    int t = threadIdx.x, d = blockIdx.x, b = blockIdx.y;
    const float* xp = x + ((size_t)(b * D_MODEL + d)) * SEQ;
    float bd = bias[d];

    {   // load + fused half=4096 (upper=0); independent per-idx rotations, full unroll
        float c0, s0;
        __sincosf((-PI_F / 4096.0f) * (float)t, &s0, &c0);
#pragma unroll
        for (int idx = 0; idx < 8; ++idx) {
            int n = t + (idx << 9);
            float2 v = ((const float2*)xp)[n];
            float cc = c0 * C8[idx] - s0 * S8n[idx];   // T0 * exp(-i*pi*idx/8)
            float ss = c0 * S8n[idx] + s0 * C8[idx];
            A[IDX(n)] = v;
            A[IDX(n + 4096)] = make_float2(v.x * cc - v.y * ss, v.x * ss + v.y * cc);
        }
    }
    __syncthreads();
    fft_fwd(A, t);

    const __half2* P = (const __half2*)(outk + (size_t)(b * D_MODEL + d) * SEQ);
    float cs, sn;
    __sincosf(-PI_F * (float)t * (1.0f / 8192.0f), &sn, &cs);
    const float cRo = 0.9807852804f, sRo = -0.1950903220f;   // exp(-i*pi/16), step 512
    for (int j = t; j <= 4096; j += 512) {
        int jm = (M - j) & (M - 1);
        int p0 = rev13(j), p1 = rev13(jm);
        int q0 = IDX(p0), q1 = IDX(p1);
        float2 z1 = A[q0], z2 = A[q1];
        float Ar_ = 0.5f * (z1.x + z2.x), Ai_ = 0.5f * (z1.y - z2.y);
        float Br_ = 0.5f * (z1.y + z2.y), Bi_ = 0.5f * (z2.x - z1.x);
        float wbr = cs * Br_ - sn * Bi_, wbi = cs * Bi_ + sn * Br_;
        float U1r = Ar_ + wbr, U1i = Ai_ + wbi;
        float U2r = Ar_ - wbr, U2i = -(Ai_ - wbi);
        float K1r, K1i, K2r, K2i;
        if (j == 0) {
            __half2 v = P[0];
            K1r = __low2float(v) + bd;  K1i = 0.f;
            K2r = __high2float(v) + bd; K2i = 0.f;
        } else {
            __half2 v1 = P[j];
            __half2 v2 = P[M - j];
            K1r = __low2float(v1) + bd; K1i = __high2float(v1);
            K2r = __low2float(v2) + bd; K2i = __high2float(v2);
        }
        float P1r = U1r * K1r - U1i * K1i, P1i = U1r * K1i + U1i * K1r;
        float P2r = U2r * K2r - U2i * K2i, P2i = U2r * K2i + U2i * K2r;
        float Er = 0.5f * (P1r + P2r), Ei = 0.5f * (P1i - P2i);
        float Or = 0.5f * (P1r - P2r), Oi = 0.5f * (P1i + P2i);
        float G = cs * Oi - sn * Or;
        float H = cs * Or + sn * Oi;
        A[q0] = make_float2(Er - G, Ei + H);
        if (j != 0) A[q1] = make_float2(Er + G, -Ei + H);
        float cn = cs * cRo - sn * sRo; sn = sn * cRo + cs * sRo; cs = cn;
    }
    __syncthreads();
    fft_inv(A, t);

    // store-fused final inverse stage (half=4096): independent per-idx rotations
    const float invM = 1.0f / 8192.0f;
    float* op = outk + ((size_t)(b * D_MODEL + d)) * SEQ;
    {
        float c0, s0;
        __sincosf((PI_F / 4096.0f) * (float)t, &s0, &c0);
#pragma unroll
        for (int idx = 0; idx < 8; ++idx) {
            int n = t + (idx << 9);
            float2 a = A[IDX(n)], bb = A[IDX(n + 4096)];
            float cc = c0 * C8[idx] - s0 * S8p[idx];   // T0 * exp(+i*pi*idx/8)
            float ss = c0 * S8p[idx] + s0 * C8[idx];
            float tr = bb.x * cc - bb.y * ss, ti = bb.x * ss + bb.y * cc;
            float2 ov;
            ov.x = (a.x + tr) * invM;
            ov.y = (a.y + ti) * invM;
            ((float2*)op)[n] = ov;
        }
    }
}

extern "C" void kernel_launch(void* const* d_in, const int* in_sizes, int n_in,
                              void* d_out, int out_size, void* d_ws, size_t ws_size,
                              hipStream_t stream)
{
    (void)in_sizes; (void)n_in; (void)out_size; (void)d_ws; (void)ws_size;
    const float* x      = (const float*)d_in[0];
    // d_in[1] = L (always 8192, hardcoded)
    const float* z      = (const float*)d_in[2];
    const float* tvec   = (const float*)d_in[3];
    const float* freq   = (const float*)d_in[4];
    const float* W1     = (const float*)d_in[5];
    const float* b1     = (const float*)d_in[6];
    const float* W2     = (const float*)d_in[7];
    const float* b2     = (const float*)d_in[8];
    const float* W3     = (const float*)d_in[9];
    const float* b3     = (const float*)d_in[10];
    const float* Wout   = (const float*)d_in[11];
    const float* deltas = (const float*)d_in[12];
    const float* bias   = (const float*)d_in[13];
    float* out = (float*)d_out;

    // staging inside d_out (12,582,912 floats):
    //   h3T (64 x 8192, transposed) -> last 64 rows of b=1 half (dead after filt)
    //   k  -> rows (0,d)   (consumed by kf block d, overwritten with packed K)
    //   K  -> rows (0,d) and (1,d) fp16-packed (consumed then overwritten by conv)
    float* h3T = out + ((size_t)(2 * D_MODEL - 64) * SEQ);
    float* k   = out;

    hipLaunchKernelGGL(mlp_kernel, dim3(SEQ / 64), dim3(256), 0, stream,
                       z, freq, W1, b1, W2, b2, W3, b3, h3T);
    hipLaunchKernelGGL(filt_kernel, dim3(SEQ / 128, D_MODEL / 64), dim3(256), 0, stream,
                       h3T, Wout, tvec, deltas, k);
    hipLaunchKernelGGL(kf_kernel, dim3(D_MODEL), dim3(512), 0, stream, out);
    hipLaunchKernelGGL(conv_kernel, dim3(D_MODEL, BATCH), dim3(512), 0, stream,
                       x, bias, out);
}

// Round 10
// 232.290 us; speedup vs baseline: 1.0823x; 1.0823x over previous
//
#include <hip/hip_runtime.h>
#include <hip/hip_fp16.h>
#include <math.h>

#define D_MODEL 768
#define EMB 33
#define ORDER 64
#define SEQ 8192
#define BATCH 2
#define M 8192      // half-size complex FFT length (N = 16384 real)

#define PI_F 3.14159265358979323846f

// padded LDS index in COMPLEX units: +1 per 16, +1 per 128
#define IDX(a) ((a) + ((a) >> 4) + ((a) >> 7))
#define LDS_SZ 8768      // complex slots; 8768*8B = 70,144 B -> 2 blocks/CU

__device__ __forceinline__ int rev13(int x) { return (int)(__brev((unsigned)x) >> 19); }

// twiddle constants for register tail/head (angle pi*k/8)
__device__ __constant__ float C8[8] = {
    1.f, 0.9238795325f, 0.7071067812f, 0.3826834324f,
    0.f, -0.3826834324f, -0.7071067812f, -0.9238795325f };
__device__ __constant__ float S8n[8] = {   // -sin(pi k/8)  (forward DIF)
    0.f, -0.3826834324f, -0.7071067812f, -0.9238795325f,
    -1.f, -0.9238795325f, -0.7071067812f, -0.3826834324f };
__device__ __constant__ float S8p[8] = {   // +sin(pi k/8)  (inverse DIT)
    0.f, 0.3826834324f, 0.7071067812f, 0.9238795325f,
    1.f, 0.9238795325f, 0.7071067812f, 0.3826834324f };

// ---------------- MLP: h3T[o][l] = sin-MLP(z[l])[o], register-tiled ----------
__global__ __launch_bounds__(256) void mlp_kernel(
    const float* __restrict__ z, const float* __restrict__ freq,
    const float* __restrict__ W1, const float* __restrict__ b1,
    const float* __restrict__ W2, const float* __restrict__ b2,
    const float* __restrict__ W3, const float* __restrict__ b3,
    float* __restrict__ h3T)
{
    __shared__ float zt[33 * 72];    // zt[e][l], rows of 72 (288B, 16B-aligned)
    __shared__ float h1[64 * 72];    // h[o][l]
    __shared__ float h2[64 * 72];
    __shared__ float Wb[64 * 68];    // W[e][o], rows of 68 (272B, 16B-aligned)
    __shared__ float sfr[64], sb[64];
    int t = threadIdx.x;
    int l0 = blockIdx.x * 64;

    for (int i = t; i < 64 * 33; i += 256) {
        int l = i / 33, e = i - l * 33;
        zt[e * 72 + l] = z[(size_t)(l0 + l) * 33 + e];
    }
    for (int i = t; i < 64 * 33; i += 256) {
        int o = i / 33, e = i - o * 33;
        Wb[e * 68 + o] = W1[i];
    }
    if (t < 64) { sfr[t] = freq[t]; sb[t] = b1[t]; }
    __syncthreads();

    int lx = t & 15, oy = t >> 4;           // 16 lx * 4l = 64 l; 16 oy * 4o = 64 o
    float fr4[4], bi4[4], acc[4][4];
#pragma unroll
    for (int i = 0; i < 4; ++i) { fr4[i] = sfr[4 * oy + i]; bi4[i] = sb[4 * oy + i]; }
#pragma unroll
    for (int c = 0; c < 4; ++c)
#pragma unroll
        for (int i = 0; i < 4; ++i) acc[c][i] = bi4[i];
    for (int e = 0; e < 33; ++e) {
        float4 hv = *(const float4*)&zt[e * 72 + 4 * lx];
        float4 wv = *(const float4*)&Wb[e * 68 + 4 * oy];
        float h[4] = {hv.x, hv.y, hv.z, hv.w}, w[4] = {wv.x, wv.y, wv.z, wv.w};
#pragma unroll
        for (int c = 0; c < 4; ++c)
#pragma unroll
            for (int i = 0; i < 4; ++i) acc[c][i] = fmaf(h[c], w[i], acc[c][i]);
    }
#pragma unroll
    for (int i = 0; i < 4; ++i) {
        float4 v = make_float4(__sinf(fr4[i] * acc[0][i]), __sinf(fr4[i] * acc[1][i]),
                               __sinf(fr4[i] * acc[2][i]), __sinf(fr4[i] * acc[3][i]));
        *(float4*)&h1[(4 * oy + i) * 72 + 4 * lx] = v;
    }
    __syncthreads();

    for (int i = t; i < 4096; i += 256) {    // W2[o][q] -> Wb[q][o]
        int o = i >> 6, q = i & 63;
        Wb[q * 68 + o] = W2[i];
    }
    if (t < 64) sb[t] = b2[t];
    __syncthreads();
#pragma unroll
    for (int i = 0; i < 4; ++i) bi4[i] = sb[4 * oy + i];
#pragma unroll
    for (int c = 0; c < 4; ++c)
#pragma unroll
        for (int i = 0; i < 4; ++i) acc[c][i] = bi4[i];
    for (int q = 0; q < 64; ++q) {
        float4 hv = *(const float4*)&h1[q * 72 + 4 * lx];
        float4 wv = *(const float4*)&Wb[q * 68 + 4 * oy];
        float h[4] = {hv.x, hv.y, hv.z, hv.w}, w[4] = {wv.x, wv.y, wv.z, wv.w};
#pragma unroll
        for (int c = 0; c < 4; ++c)
#pragma unroll
            for (int i = 0; i < 4; ++i) acc[c][i] = fmaf(h[c], w[i], acc[c][i]);
    }
#pragma unroll
    for (int i = 0; i < 4; ++i) {
        float4 v = make_float4(__sinf(fr4[i] * acc[0][i]), __sinf(fr4[i] * acc[1][i]),
                               __sinf(fr4[i] * acc[2][i]), __sinf(fr4[i] * acc[3][i]));
        *(float4*)&h2[(4 * oy + i) * 72 + 4 * lx] = v;
    }
    __syncthreads();

    for (int i = t; i < 4096; i += 256) {    // W3[o][q] -> Wb[q][o]
        int o = i >> 6, q = i & 63;
        Wb[q * 68 + o] = W3[i];
    }
    if (t < 64) sb[t] = b3[t];
    __syncthreads();
#pragma unroll
    for (int i = 0; i < 4; ++i) bi4[i] = sb[4 * oy + i];
#pragma unroll
    for (int c = 0; c < 4; ++c)
#pragma unroll
        for (int i = 0; i < 4; ++i) acc[c][i] = bi4[i];
    for (int q = 0; q < 64; ++q) {
        float4 hv = *(const float4*)&h2[q * 72 + 4 * lx];
        float4 wv = *(const float4*)&Wb[q * 68 + 4 * oy];
        float h[4] = {hv.x, hv.y, hv.z, hv.w}, w[4] = {wv.x, wv.y, wv.z, wv.w};
#pragma unroll
        for (int c = 0; c < 4; ++c)
#pragma unroll
            for (int i = 0; i < 4; ++i) acc[c][i] = fmaf(h[c], w[i], acc[c][i]);
    }
#pragma unroll
    for (int i = 0; i < 4; ++i) {
        float4 v = make_float4(__sinf(fr4[i] * acc[0][i]), __sinf(fr4[i] * acc[1][i]),
                               __sinf(fr4[i] * acc[2][i]), __sinf(fr4[i] * acc[3][i]));
        *(float4*)&h3T[(size_t)(4 * oy + i) * SEQ + l0 + 4 * lx] = v;
    }
}

// ------- filter: k[d][l] = (h3[l]·Wout[d]) * exp(-t[l]*|delta[d]|), tiled -------
__global__ __launch_bounds__(256) void filt_kernel(
    const float* __restrict__ h3T, const float* __restrict__ Wout,
    const float* __restrict__ tvec, const float* __restrict__ deltas,
    float* __restrict__ kout)
{
    __shared__ float ht[64 * 132];   // ht[kk][l], rows 132 (528B, 16B-aligned)
    __shared__ float wt[64 * 68];    // wt[kk][dd], rows 68
    int t = threadIdx.x;
    int l0 = blockIdx.x * 128, d0 = blockIdx.y * 64;

    for (int i = t; i < 64 * 128; i += 256) {
        int o = i >> 7, l = i & 127;
        ht[o * 132 + l] = h3T[(size_t)o * SEQ + l0 + l];
    }
    for (int i = t; i < 4096; i += 256) {    // Wout[d][kk] -> wt[kk][dd]
        int dd = i >> 6, kk = i & 63;
        wt[kk * 68 + dd] = Wout[(size_t)(d0 + dd) * 64 + kk];
    }
    __syncthreads();

    int lx = t & 31, dy = t >> 5;            // 32 lx * 4l = 128; 8 dy * 8d = 64
    float acc[4][8];
#pragma unroll
    for (int c = 0; c < 4; ++c)
#pragma unroll
        for (int i = 0; i < 8; ++i) acc[c][i] = 0.f;
    for (int kk = 0; kk < 64; ++kk) {
        float4 hv = *(const float4*)&ht[kk * 132 + 4 * lx];
        float4 w0 = *(const float4*)&wt[kk * 68 + 8 * dy];
        float4 w1 = *(const float4*)&wt[kk * 68 + 8 * dy + 4];
        float h[4] = {hv.x, hv.y, hv.z, hv.w};
        float w[8] = {w0.x, w0.y, w0.z, w0.w, w1.x, w1.y, w1.z, w1.w};
#pragma unroll
        for (int c = 0; c < 4; ++c)
#pragma unroll
            for (int i = 0; i < 8; ++i) acc[c][i] = fmaf(h[c], w[i], acc[c][i]);
    }

    float4 tl4 = *(const float4*)&tvec[l0 + 4 * lx];
    float tl[4] = {tl4.x, tl4.y, tl4.z, tl4.w};
    float del[8];
#pragma unroll
    for (int i = 0; i < 8; ++i) del[i] = fabsf(deltas[d0 + 8 * dy + i]);
#pragma unroll
    for (int i = 0; i < 8; ++i) {
        int d = d0 + 8 * dy + i;
        float4 v = make_float4(acc[0][i] * __expf(-tl[0] * del[i]),
                               acc[1][i] * __expf(-tl[1] * del[i]),
                               acc[2][i] * __expf(-tl[2] * del[i]),
                               acc[3][i] * __expf(-tl[3] * del[i]));
        *(float4*)&kout[(size_t)d * SEQ + l0 + 4 * lx] = v;
    }
}

// ---------------- radix-8 fused forward pass: stages (H, H/2, H/4) ---------------
// A is interleaved complex (float2), padded in complex units.
template<int H>
__device__ __forceinline__ void fwd8(float2* A, int t)
{
    constexpr int H4 = H / 4;
    int j0 = t & (H4 - 1);
    float c1, s1;
    __sincosf((-PI_F / (float)H) * (float)j0, &s1, &c1);
#pragma unroll
    for (int gg = 0; gg < 2; ++gg) {
        int g = t + (gg << 9);
        int j = g & (H4 - 1);
        int i = ((g & ~(H4 - 1)) << 3) | j;
        float c1g = c1, s1g = s1;
        if (H4 > 512 && gg == 1) {       // only H=4096: j differs by 512 -> rotate T1
            const float cR = 0.9238795325f, sR = -0.3826834324f;  // exp(-i*pi/8)
            c1g = c1 * cR - s1 * sR;
            s1g = s1 * cR + c1 * sR;
        }
        float c2 = c1g * c1g - s1g * s1g, s2 = 2.f * c1g * s1g;   // T1^2
        float c3 = c2 * c2 - s2 * s2,     s3 = 2.f * c2 * s2;     // T1^4
        float xr[8], xi[8];
        int ad[8];
#pragma unroll
        for (int m = 0; m < 8; ++m) {
            ad[m] = IDX(i + m * H4);
            float2 v = A[ad[m]];
            xr[m] = v.x; xi[m] = v.y;
        }
        const float r = 0.70710678118f;
        float twc[4], tws[4];                                      // T1 * W8^m
        twc[0] = c1g;             tws[0] = s1g;
        twc[1] = r * (c1g + s1g); tws[1] = r * (s1g - c1g);
        twc[2] = s1g;             tws[2] = -c1g;
        twc[3] = r * (s1g - c1g); tws[3] = -r * (c1g + s1g);
#pragma unroll
        for (int m = 0; m < 4; ++m) {                              // stage half=H
            float ur = xr[m] + xr[m + 4], ui = xi[m] + xi[m + 4];
            float dr = xr[m] - xr[m + 4], di = xi[m] - xi[m + 4];
            xr[m] = ur; xi[m] = ui;
            xr[m + 4] = dr * twc[m] - di * tws[m];
            xi[m + 4] = dr * tws[m] + di * twc[m];
        }
#pragma unroll
        for (int base = 0; base < 8; base += 4)                    // stage half=H/2
#pragma unroll
            for (int mm = 0; mm < 2; ++mm) {
                int a = base + mm, b = a + 2;
                float ur = xr[a] + xr[b], ui = xi[a] + xi[b];
                float dr = xr[a] - xr[b], di = xi[a] - xi[b];
                xr[a] = ur; xi[a] = ui;
                if (mm == 0) { xr[b] = dr * c2 - di * s2; xi[b] = dr * s2 + di * c2; }
                else         { xr[b] = dr * s2 + di * c2; xi[b] = di * s2 - dr * c2; }  // *T2*(-i)
            }
#pragma unroll
        for (int m = 0; m < 8; m += 2) {                           // stage half=H/4
            float ur = xr[m] + xr[m + 1], ui = xi[m] + xi[m + 1];
            float dr = xr[m] - xr[m + 1], di = xi[m] - xi[m + 1];
            xr[m] = ur; xi[m] = ui;
            xr[m + 1] = dr * c3 - di * s3; xi[m + 1] = dr * s3 + di * c3;
        }
#pragma unroll
        for (int m = 0; m < 8; ++m) A[ad[m]] = make_float2(xr[m], xi[m]);
    }
}

// ---------------- radix-8 fused inverse pass: stages (H, 2H, 4H) -----------------
template<int H>
__device__ __forceinline__ void inv8(float2* A, int t)
{
    int j0 = t & (H - 1);
    float ct, st;
    __sincosf((PI_F / (float)(4 * H)) * (float)j0, &st, &ct);      // T = exp(i pi j/(4H))
#pragma unroll
    for (int gg = 0; gg < 2; ++gg) {
        int g = t + (gg << 9);
        int j = g & (H - 1);
        int i = ((g & ~(H - 1)) << 3) | j;
        float c = ct, s = st;
        if (H > 512 && gg == 1) {        // only H=1024: j differs by 512 -> rotate T
            const float cR = 0.9238795325f, sR = 0.3826834324f;    // exp(+i*pi/8)
            c = ct * cR - st * sR;
            s = st * cR + ct * sR;
        }
        float c2 = c * c - s * s, s2 = 2.f * c * s;                // T^2
        float c4 = c2 * c2 - s2 * s2, s4 = 2.f * c2 * s2;          // T^4
        float xr[8], xi[8]; int ad[8];
#pragma unroll
        for (int m = 0; m < 8; ++m) {
            ad[m] = IDX(i + m * H);
            float2 v = A[ad[m]];
            xr[m] = v.x; xi[m] = v.y;
        }
#pragma unroll
        for (int m = 0; m < 8; m += 2) {
            float tr = xr[m + 1] * c4 - xi[m + 1] * s4;
            float ti = xr[m + 1] * s4 + xi[m + 1] * c4;
            xr[m + 1] = xr[m] - tr; xi[m + 1] = xi[m] - ti;
            xr[m]     = xr[m] + tr; xi[m]     = xi[m] + ti;
        }
#pragma unroll
        for (int base = 0; base < 8; base += 4)
#pragma unroll
            for (int mm = 0; mm < 2; ++mm) {
                int a = base + mm, b = a + 2;
                float tr, ti;
                if (mm == 0) { tr = xr[b] * c2 - xi[b] * s2; ti = xr[b] * s2 + xi[b] * c2; }
                else         { tr = -(xr[b] * s2 + xi[b] * c2); ti = xr[b] * c2 - xi[b] * s2; }
                xr[b] = xr[a] - tr; xi[b] = xi[a] - ti;
                xr[a] = xr[a] + tr; xi[a] = xi[a] + ti;
            }
        const float r = 0.70710678118f;
        float t3c[4], t3s[4];
        t3c[0] = c;           t3s[0] = s;
        t3c[1] = r * (c - s); t3s[1] = r * (c + s);
        t3c[2] = -s;          t3s[2] = c;
        t3c[3] = -r * (c + s); t3s[3] = r * (c - s);
#pragma unroll
        for (int m = 0; m < 4; ++m) {
            float tr = xr[m + 4] * t3c[m] - xi[m + 4] * t3s[m];
            float ti = xr[m + 4] * t3s[m] + xi[m + 4] * t3c[m];
            xr[m + 4] = xr[m] - tr; xi[m + 4] = xi[m] - ti;
            xr[m]     = xr[m] + tr; xi[m]     = xi[m] + ti;
        }
#pragma unroll
        for (int m = 0; m < 8; ++m) A[ad[m]] = make_float2(xr[m], xi[m]);
    }
}

// ---------------- forward FFT: 3 radix-8 LDS passes + register tail --------------
__device__ __forceinline__ void fft_fwd(float2* A, int t)
{
    fwd8<4096>(A, t); __syncthreads();
    fwd8<512>(A, t);  __syncthreads();
    fwd8<64>(A, t);   __syncthreads();
    {
        int pb = IDX(16 * t);
        float fr[16], fi[16];
#pragma unroll
        for (int e = 0; e < 16; ++e) { float2 v = A[pb + e]; fr[e] = v.x; fi[e] = v.y; }
#pragma unroll
        for (int k = 0; k < 8; ++k) {
            float cs = C8[k], sn = S8n[k];
            float arr = fr[k], aii = fi[k], brr = fr[k + 8], bii = fi[k + 8];
            fr[k] = arr + brr; fi[k] = aii + bii;
            float dr = arr - brr, di = aii - bii;
            fr[k + 8] = dr * cs - di * sn; fi[k + 8] = dr * sn + di * cs;
        }
#pragma unroll
        for (int b0 = 0; b0 < 16; b0 += 8)
#pragma unroll
            for (int k = 0; k < 4; ++k) {
                float cs = C8[2 * k], sn = S8n[2 * k];
                int i0 = b0 + k, i1 = i0 + 4;
                float arr = fr[i0], aii = fi[i0], brr = fr[i1], bii = fi[i1];
                fr[i0] = arr + brr; fi[i0] = aii + bii;
                float dr = arr - brr, di = aii - bii;
                fr[i1] = dr * cs - di * sn; fi[i1] = dr * sn + di * cs;
            }
#pragma unroll
        for (int b0 = 0; b0 < 16; b0 += 4)
#pragma unroll
            for (int k = 0; k < 2; ++k) {
                float cs = C8[4 * k], sn = S8n[4 * k];
                int i0 = b0 + k, i1 = i0 + 2;
                float arr = fr[i0], aii = fi[i0], brr = fr[i1], bii = fi[i1];
                fr[i0] = arr + brr; fi[i0] = aii + bii;
                float dr = arr - brr, di = aii - bii;
                fr[i1] = dr * cs - di * sn; fi[i1] = dr * sn + di * cs;
            }
#pragma unroll
        for (int b0 = 0; b0 < 16; b0 += 2) {
            float arr = fr[b0], aii = fi[b0], brr = fr[b0 + 1], bii = fi[b0 + 1];
            fr[b0] = arr + brr; fi[b0] = aii + bii;
            fr[b0 + 1] = arr - brr; fi[b0 + 1] = aii - bii;
        }
#pragma unroll
        for (int e = 0; e < 16; ++e) A[pb + e] = make_float2(fr[e], fi[e]);
        __syncthreads();
    }
}

// ---------------- inverse FFT: register head + 3 radix-8 LDS passes --------------
__device__ __forceinline__ void fft_inv(float2* A, int t)
{
    {
        int pb = IDX(16 * t);
        float fr[16], fi[16];
#pragma unroll
        for (int e = 0; e < 16; ++e) { float2 v = A[pb + e]; fr[e] = v.x; fi[e] = v.y; }
#pragma unroll
        for (int b0 = 0; b0 < 16; b0 += 2) {
            float arr = fr[b0], aii = fi[b0], brr = fr[b0 + 1], bii = fi[b0 + 1];
            fr[b0] = arr + brr; fi[b0] = aii + bii;
            fr[b0 + 1] = arr - brr; fi[b0 + 1] = aii - bii;
        }
#pragma unroll
        for (int b0 = 0; b0 < 16; b0 += 4)
#pragma unroll
            for (int k = 0; k < 2; ++k) {
                float cs = C8[4 * k], sn = S8p[4 * k];
                int i0 = b0 + k, i1 = i0 + 2;
                float arr = fr[i0], aii = fi[i0], brr = fr[i1], bii = fi[i1];
                float tr = brr * cs - bii * sn, ti = brr * sn + bii * cs;
                fr[i0] = arr + tr; fi[i0] = aii + ti;
                fr[i1] = arr - tr; fi[i1] = aii - ti;
            }
#pragma unroll
        for (int b0 = 0; b0 < 16; b0 += 8)
#pragma unroll
            for (int k = 0; k < 4; ++k) {
                float cs = C8[2 * k], sn = S8p[2 * k];
                int i0 = b0 + k, i1 = i0 + 4;
                float arr = fr[i0], aii = fi[i0], brr = fr[i1], bii = fi[i1];
                float tr = brr * cs - bii * sn, ti = brr * sn + bii * cs;
                fr[i0] = arr + tr; fi[i0] = aii + ti;
                fr[i1] = arr - tr; fi[i1] = aii - ti;
            }
#pragma unroll
        for (int k = 0; k < 8; ++k) {
            float cs = C8[k], sn = S8p[k];
            float arr = fr[k], aii = fi[k], brr = fr[k + 8], bii = fi[k + 8];
            float tr = brr * cs - bii * sn, ti = brr * sn + bii * cs;
            fr[k] = arr + tr; fi[k] = aii + ti;
            fr[k + 8] = arr - tr; fi[k + 8] = aii - ti;
        }
#pragma unroll
        for (int e = 0; e < 16; ++e) A[pb + e] = make_float2(fr[e], fi[e]);
        __syncthreads();
    }
    inv8<16>(A, t);   __syncthreads();
    inv8<128>(A, t);  __syncthreads();
    inv8<1024>(A, t); __syncthreads();
}

// ---------------- kf: K_f[d] = rfft(k_d, 16384), fp16-packed -------------------
// kb0/kb1: destination row bases. If kb1 == kb0 (workspace mode) the duplicate
// write is skipped (conv reads the single copy for both batches).
__global__ __launch_bounds__(512, 4) void kf_kernel(
    float* outk, float* kb0, float* kb1)
{
    __shared__ float2 A[LDS_SZ];
    int t = threadIdx.x, d = blockIdx.x;
    const float* kp = outk + (size_t)d * SEQ;
    for (int n = t; n < 4096; n += 512) {
        A[IDX(n)] = ((const float2*)kp)[n];
    }
    for (int n = 4096 + t; n < M; n += 512) A[IDX(n)] = make_float2(0.f, 0.f);
    __syncthreads();
    fft_fwd(A, t);

    __half2* P0 = (__half2*)(kb0 + (size_t)d * SEQ);
    __half2* P1 = (__half2*)(kb1 + (size_t)d * SEQ);
    bool dup = (kb1 != kb0);
    float cs, sn;
    __sincosf(-PI_F * (float)t * (1.0f / 8192.0f), &sn, &cs);
    const float cRo = 0.9807852804f, sRo = -0.1950903220f;   // exp(-i*pi/16)
    for (int j = t; j <= 4096; j += 512) {
        int jm = (M - j) & (M - 1);
        int p0 = rev13(j), p1 = rev13(jm);
        float2 z1 = A[IDX(p0)], z2 = A[IDX(p1)];
        float Ar_ = 0.5f * (z1.x + z2.x), Ai_ = 0.5f * (z1.y - z2.y);
        float Br_ = 0.5f * (z1.y + z2.y), Bi_ = 0.5f * (z2.x - z1.x);
        float wbr = cs * Br_ - sn * Bi_, wbi = cs * Bi_ + sn * Br_;
        float K1r = Ar_ + wbr, K1i = Ai_ + wbi;
        float K2r = Ar_ - wbr, K2i = -(Ai_ - wbi);
        if (j == 0) {
            __half2 v = __floats2half2_rn(K1r, K2r);
            P0[0] = v; if (dup) P1[0] = v;
        } else {
            __half2 v1 = __floats2half2_rn(K1r, K1i);
            P0[j] = v1; if (dup) P1[j] = v1;
            if (j != 4096) {
                __half2 v2 = __floats2half2_rn(K2r, K2i);
                P0[M - j] = v2; if (dup) P1[M - j] = v2;
            }
        }
        float cn = cs * cRo - sn * sRo; sn = sn * cRo + cs * sRo; cs = cn;
    }
}

// ---------------- conv: block (d,b): y = irfft(rfft(x)*(K + bias_d))[:8192] ------
// bias fold: y + x*bias_d == irfft(U_f * (K_f + bias_d))[:8192] (bias*delta0 has a
// flat real spectrum; irfft(rfft(x,2L),2L)[:L]==x exactly for zero-padded x).
// K row = kbase + (b*kstride + d)*SEQ; kstride=0 in workspace (shared-K) mode.
__global__ __launch_bounds__(512, 4) void conv_kernel(
    const float* __restrict__ x, const float* __restrict__ bias,
    float* outk, const float* __restrict__ kbase, int kstride)
{
    __shared__ float2 A[LDS_SZ];
    int t = threadIdx.x, d = blockIdx.x, b = blockIdx.y;
    const float* xp = x + ((size_t)(b * D_MODEL + d)) * SEQ;
    float bd = bias[d];

#pragma unroll
    for (int idx = 0; idx < 8; ++idx) {
        int n = t + (idx << 9);
        A[IDX(n)] = ((const float2*)xp)[n];
    }
    for (int n = 4096 + t; n < M; n += 512) A[IDX(n)] = make_float2(0.f, 0.f);
    __syncthreads();
    fft_fwd(A, t);

    const __half2* P = (const __half2*)(kbase + (size_t)(b * kstride + d) * SEQ);
    float cs, sn;
    __sincosf(-PI_F * (float)t * (1.0f / 8192.0f), &sn, &cs);
    const float cRo = 0.9807852804f, sRo = -0.1950903220f;   // exp(-i*pi/16)
    for (int j = t; j <= 4096; j += 512) {
        int jm = (M - j) & (M - 1);
        int p0 = rev13(j), p1 = rev13(jm);
        int q0 = IDX(p0), q1 = IDX(p1);
        float2 z1 = A[q0], z2 = A[q1];
        float Ar_ = 0.5f * (z1.x + z2.x), Ai_ = 0.5f * (z1.y - z2.y);
        float Br_ = 0.5f * (z1.y + z2.y), Bi_ = 0.5f * (z2.x - z1.x);
        float wbr = cs * Br_ - sn * Bi_, wbi = cs * Bi_ + sn * Br_;
        float U1r = Ar_ + wbr, U1i = Ai_ + wbi;
        float U2r = Ar_ - wbr, U2i = -(Ai_ - wbi);
        float K1r, K1i, K2r, K2i;
        if (j == 0) {
            __half2 v = P[0];
            K1r = __low2float(v) + bd;  K1i = 0.f;
            K2r = __high2float(v) + bd; K2i = 0.f;
        } else {
            __half2 v1 = P[j];
            __half2 v2 = P[M - j];
            K1r = __low2float(v1) + bd; K1i = __high2float(v1);
            K2r = __low2float(v2) + bd; K2i = __high2float(v2);
        }
        float P1r = U1r * K1r - U1i * K1i, P1i = U1r * K1i + U1i * K1r;
        float P2r = U2r * K2r - U2i * K2i, P2i = U2r * K2i + U2i * K2r;
        float Er = 0.5f * (P1r + P2r), Ei = 0.5f * (P1i - P2i);
        float Or = 0.5f * (P1r - P2r), Oi = 0.5f * (P1i + P2i);
        float G = cs * Oi - sn * Or;
        float H = cs * Or + sn * Oi;
        A[q0] = make_float2(Er - G, Ei + H);
        if (j != 0) A[q1] = make_float2(Er + G, -Ei + H);
        float cn = cs * cRo - sn * sRo; sn = sn * cRo + cs * sRo; cs = cn;
    }
    __syncthreads();
    fft_inv(A, t);

    const float invM = 1.0f / 8192.0f;
    float* op = outk + ((size_t)(b * D_MODEL + d)) * SEQ;
#pragma unroll
    for (int idx = 0; idx < 8; ++idx) {
        int n = t + (idx << 9);
        float2 v = A[IDX(n)];
        float2 ov;
        ov.x = v.x * invM;
        ov.y = v.y * invM;
        ((float2*)op)[n] = ov;
    }
}

extern "C" void kernel_launch(void* const* d_in, const int* in_sizes, int n_in,
                              void* d_out, int out_size, void* d_ws, size_t ws_size,
                              hipStream_t stream)
{
    (void)in_sizes; (void)n_in; (void)out_size;
    const float* x      = (const float*)d_in[0];
    // d_in[1] = L (always 8192, hardcoded)
    const float* z      = (const float*)d_in[2];
    const float* tvec   = (const float*)d_in[3];
    const float* freq   = (const float*)d_in[4];
    const float* W1     = (const float*)d_in[5];
    const float* b1     = (const float*)d_in[6];
    const float* W2     = (const float*)d_in[7];
    const float* b2     = (const float*)d_in[8];
    const float* W3     = (const float*)d_in[9];
    const float* b3     = (const float*)d_in[10];
    const float* Wout   = (const float*)d_in[11];
    const float* deltas = (const float*)d_in[12];
    const float* bias   = (const float*)d_in[13];
    float* out = (float*)d_out;

    // staging inside d_out (12,582,912 floats):
    //   h3T (64 x 8192, transposed) -> last 64 rows of b=1 half (dead after filt)
    //   k  -> rows (0,d)   (consumed by kf block d)
    //   K packed fp16: in workspace (single copy, shared by both batches) when
    //   ws_size permits; else duplicated into rows (0,d) and (1,d) of d_out
    //   exactly as before (conv(b) overwrites its own K row with output).
    float* h3T = out + ((size_t)(2 * D_MODEL - 64) * SEQ);
    float* k   = out;

    const size_t kbytes = (size_t)D_MODEL * SEQ * sizeof(float);  // 25.2 MB packed K
    bool usews = (d_ws != nullptr) && (ws_size >= kbytes);
    float* kws = (float*)d_ws;
    float* kb0 = usews ? kws : out;
    float* kb1 = usews ? kws : out + (size_t)D_MODEL * SEQ;
    const float* kbase = usews ? kws : out;
    int kstride = usews ? 0 : D_MODEL;

    hipLaunchKernelGGL(mlp_kernel, dim3(SEQ / 64), dim3(256), 0, stream,
                       z, freq, W1, b1, W2, b2, W3, b3, h3T);
    hipLaunchKernelGGL(filt_kernel, dim3(SEQ / 128, D_MODEL / 64), dim3(256), 0, stream,
                       h3T, Wout, tvec, deltas, k);
    hipLaunchKernelGGL(kf_kernel, dim3(D_MODEL), dim3(512), 0, stream,
                       out, kb0, kb1);
    hipLaunchKernelGGL(conv_kernel, dim3(D_MODEL, BATCH), dim3(512), 0, stream,
                       x, bias, out, kbase, kstride);
}

// Round 11
// 230.513 us; speedup vs baseline: 1.0906x; 1.0077x over previous
//
#include <hip/hip_runtime.h>
#include <hip/hip_fp16.h>
#include <math.h>

#define D_MODEL 768
#define EMB 33
#define ORDER 64
#define SEQ 8192
#define BATCH 2
#define M 8192      // half-size complex FFT length (N = 16384 real)

#define PI_F 3.14159265358979323846f

// padded LDS index in COMPLEX units: +1 per 16, +1 per 128
#define IDX(a) ((a) + ((a) >> 4) + ((a) >> 7))
#define LDS_SZ 8768      // complex slots; 8768*8B = 70,144 B -> 2 blocks/CU

__device__ __forceinline__ int rev13(int x) { return (int)(__brev((unsigned)x) >> 19); }

// twiddle constants for register tail/head (angle pi*k/8)
__device__ __constant__ float C8[8] = {
    1.f, 0.9238795325f, 0.7071067812f, 0.3826834324f,
    0.f, -0.3826834324f, -0.7071067812f, -0.9238795325f };
__device__ __constant__ float S8n[8] = {   // -sin(pi k/8)  (forward DIF)
    0.f, -0.3826834324f, -0.7071067812f, -0.9238795325f,
    -1.f, -0.9238795325f, -0.7071067812f, -0.3826834324f };
__device__ __constant__ float S8p[8] = {   // +sin(pi k/8)  (inverse DIT)
    0.f, 0.3826834324f, 0.7071067812f, 0.9238795325f,
    1.f, 0.9238795325f, 0.7071067812f, 0.3826834324f };

// ---------------- MLP: h3T[o][l] = sin-MLP(z[l])[o], register-tiled ----------
__global__ __launch_bounds__(256) void mlp_kernel(
    const float* __restrict__ z, const float* __restrict__ freq,
    const float* __restrict__ W1, const float* __restrict__ b1,
    const float* __restrict__ W2, const float* __restrict__ b2,
    const float* __restrict__ W3, const float* __restrict__ b3,
    float* __restrict__ h3T)
{
    __shared__ float zt[33 * 72];    // zt[e][l], rows of 72 (288B, 16B-aligned)
    __shared__ float h1[64 * 72];    // h[o][l]
    __shared__ float h2[64 * 72];
    __shared__ float Wb[64 * 68];    // W[e][o], rows of 68 (272B, 16B-aligned)
    __shared__ float sfr[64], sb[64];
    int t = threadIdx.x;
    int l0 = blockIdx.x * 64;

    for (int i = t; i < 64 * 33; i += 256) {
        int l = i / 33, e = i - l * 33;
        zt[e * 72 + l] = z[(size_t)(l0 + l) * 33 + e];
    }
    for (int i = t; i < 64 * 33; i += 256) {
        int o = i / 33, e = i - o * 33;
        Wb[e * 68 + o] = W1[i];
    }
    if (t < 64) { sfr[t] = freq[t]; sb[t] = b1[t]; }
    __syncthreads();

    int lx = t & 15, oy = t >> 4;           // 16 lx * 4l = 64 l; 16 oy * 4o = 64 o
    float fr4[4], bi4[4], acc[4][4];
#pragma unroll
    for (int i = 0; i < 4; ++i) { fr4[i] = sfr[4 * oy + i]; bi4[i] = sb[4 * oy + i]; }
#pragma unroll
    for (int c = 0; c < 4; ++c)
#pragma unroll
        for (int i = 0; i < 4; ++i) acc[c][i] = bi4[i];
    for (int e = 0; e < 33; ++e) {
        float4 hv = *(const float4*)&zt[e * 72 + 4 * lx];
        float4 wv = *(const float4*)&Wb[e * 68 + 4 * oy];
        float h[4] = {hv.x, hv.y, hv.z, hv.w}, w[4] = {wv.x, wv.y, wv.z, wv.w};
#pragma unroll
        for (int c = 0; c < 4; ++c)
#pragma unroll
            for (int i = 0; i < 4; ++i) acc[c][i] = fmaf(h[c], w[i], acc[c][i]);
    }
#pragma unroll
    for (int i = 0; i < 4; ++i) {
        float4 v = make_float4(__sinf(fr4[i] * acc[0][i]), __sinf(fr4[i] * acc[1][i]),
                               __sinf(fr4[i] * acc[2][i]), __sinf(fr4[i] * acc[3][i]));
        *(float4*)&h1[(4 * oy + i) * 72 + 4 * lx] = v;
    }
    __syncthreads();

    for (int i = t; i < 4096; i += 256) {    // W2[o][q] -> Wb[q][o]
        int o = i >> 6, q = i & 63;
        Wb[q * 68 + o] = W2[i];
    }
    if (t < 64) sb[t] = b2[t];
    __syncthreads();
#pragma unroll
    for (int i = 0; i < 4; ++i) bi4[i] = sb[4 * oy + i];
#pragma unroll
    for (int c = 0; c < 4; ++c)
#pragma unroll
        for (int i = 0; i < 4; ++i) acc[c][i] = bi4[i];
    for (int q = 0; q < 64; ++q) {
        float4 hv = *(const float4*)&h1[q * 72 + 4 * lx];
        float4 wv = *(const float4*)&Wb[q * 68 + 4 * oy];
        float h[4] = {hv.x, hv.y, hv.z, hv.w}, w[4] = {wv.x, wv.y, wv.z, wv.w};
#pragma unroll
        for (int c = 0; c < 4; ++c)
#pragma unroll
            for (int i = 0; i < 4; ++i) acc[c][i] = fmaf(h[c], w[i], acc[c][i]);
    }
#pragma unroll
    for (int i = 0; i < 4; ++i) {
        float4 v = make_float4(__sinf(fr4[i] * acc[0][i]), __sinf(fr4[i] * acc[1][i]),
                               __sinf(fr4[i] * acc[2][i]), __sinf(fr4[i] * acc[3][i]));
        *(float4*)&h2[(4 * oy + i) * 72 + 4 * lx] = v;
    }
    __syncthreads();

    for (int i = t; i < 4096; i += 256) {    // W3[o][q] -> Wb[q][o]
        int o = i >> 6, q = i & 63;
        Wb[q * 68 + o] = W3[i];
    }
    if (t < 64) sb[t] = b3[t];
    __syncthreads();
#pragma unroll
    for (int i = 0; i < 4; ++i) bi4[i] = sb[4 * oy + i];
#pragma unroll
    for (int c = 0; c < 4; ++c)
#pragma unroll
        for (int i = 0; i < 4; ++i) acc[c][i] = bi4[i];
    for (int q = 0; q < 64; ++q) {
        float4 hv = *(const float4*)&h2[q * 72 + 4 * lx];
        float4 wv = *(const float4*)&Wb[q * 68 + 4 * oy];
        float h[4] = {hv.x, hv.y, hv.z, hv.w}, w[4] = {wv.x, wv.y, wv.z, wv.w};
#pragma unroll
        for (int c = 0; c < 4; ++c)
#pragma unroll
            for (int i = 0; i < 4; ++i) acc[c][i] = fmaf(h[c], w[i], acc[c][i]);
    }
#pragma unroll
    for (int i = 0; i < 4; ++i) {
        float4 v = make_float4(__sinf(fr4[i] * acc[0][i]), __sinf(fr4[i] * acc[1][i]),
                               __sinf(fr4[i] * acc[2][i]), __sinf(fr4[i] * acc[3][i]));
        *(float4*)&h3T[(size_t)(4 * oy + i) * SEQ + l0 + 4 * lx] = v;
    }
}

// ------- filter: k[d][l] = (h3[l]·Wout[d]) * exp(-t[l]*|delta[d]|), tiled -------
__global__ __launch_bounds__(256) void filt_kernel(
    const float* __restrict__ h3T, const float* __restrict__ Wout,
    const float* __restrict__ tvec, const float* __restrict__ deltas,
    float* __restrict__ kout)
{
    __shared__ float ht[64 * 132];   // ht[kk][l], rows 132 (528B, 16B-aligned)
    __shared__ float wt[64 * 68];    // wt[kk][dd], rows 68
    int t = threadIdx.x;
    int l0 = blockIdx.x * 128, d0 = blockIdx.y * 64;

    for (int i = t; i < 64 * 128; i += 256) {
        int o = i >> 7, l = i & 127;
        ht[o * 132 + l] = h3T[(size_t)o * SEQ + l0 + l];
    }
    for (int i = t; i < 4096; i += 256) {    // Wout[d][kk] -> wt[kk][dd]
        int dd = i >> 6, kk = i & 63;
        wt[kk * 68 + dd] = Wout[(size_t)(d0 + dd) * 64 + kk];
    }
    __syncthreads();

    int lx = t & 31, dy = t >> 5;            // 32 lx * 4l = 128; 8 dy * 8d = 64
    float acc[4][8];
#pragma unroll
    for (int c = 0; c < 4; ++c)
#pragma unroll
        for (int i = 0; i < 8; ++i) acc[c][i] = 0.f;
    for (int kk = 0; kk < 64; ++kk) {
        float4 hv = *(const float4*)&ht[kk * 132 + 4 * lx];
        float4 w0 = *(const float4*)&wt[kk * 68 + 8 * dy];
        float4 w1 = *(const float4*)&wt[kk * 68 + 8 * dy + 4];
        float h[4] = {hv.x, hv.y, hv.z, hv.w};
        float w[8] = {w0.x, w0.y, w0.z, w0.w, w1.x, w1.y, w1.z, w1.w};
#pragma unroll
        for (int c = 0; c < 4; ++c)
#pragma unroll
            for (int i = 0; i < 8; ++i) acc[c][i] = fmaf(h[c], w[i], acc[c][i]);
    }

    float4 tl4 = *(const float4*)&tvec[l0 + 4 * lx];
    float tl[4] = {tl4.x, tl4.y, tl4.z, tl4.w};
    float del[8];
#pragma unroll
    for (int i = 0; i < 8; ++i) del[i] = fabsf(deltas[d0 + 8 * dy + i]);
#pragma unroll
    for (int i = 0; i < 8; ++i) {
        int d = d0 + 8 * dy + i;
        float4 v = make_float4(acc[0][i] * __expf(-tl[0] * del[i]),
                               acc[1][i] * __expf(-tl[1] * del[i]),
                               acc[2][i] * __expf(-tl[2] * del[i]),
                               acc[3][i] * __expf(-tl[3] * del[i]));
        *(float4*)&kout[(size_t)d * SEQ + l0 + 4 * lx] = v;
    }
}

// -------- single-group radix-8 forward: stages (H, H/2, H/4) at base index i ----
// Body is verbatim the R3/R10 per-gg stage code; twiddle T1=(c1,s1) passed in.
template<int H>
__device__ __forceinline__ void fwd8g1(float2* A, int i, float c1, float s1)
{
    constexpr int H4 = H / 4;
    float c2 = c1 * c1 - s1 * s1, s2 = 2.f * c1 * s1;   // T1^2
    float c3 = c2 * c2 - s2 * s2, s3 = 2.f * c2 * s2;   // T1^4
    float xr[8], xi[8];
    int ad[8];
#pragma unroll
    for (int m = 0; m < 8; ++m) {
        ad[m] = IDX(i + m * H4);
        float2 v = A[ad[m]];
        xr[m] = v.x; xi[m] = v.y;
    }
    const float r = 0.70710678118f;
    float twc[4], tws[4];                                // T1 * W8^m
    twc[0] = c1;            tws[0] = s1;
    twc[1] = r * (c1 + s1); tws[1] = r * (s1 - c1);
    twc[2] = s1;            tws[2] = -c1;
    twc[3] = r * (s1 - c1); tws[3] = -r * (c1 + s1);
#pragma unroll
    for (int m = 0; m < 4; ++m) {                        // stage half=H
        float ur = xr[m] + xr[m + 4], ui = xi[m] + xi[m + 4];
        float dr = xr[m] - xr[m + 4], di = xi[m] - xi[m + 4];
        xr[m] = ur; xi[m] = ui;
        xr[m + 4] = dr * twc[m] - di * tws[m];
        xi[m + 4] = dr * tws[m] + di * twc[m];
    }
#pragma unroll
    for (int base = 0; base < 8; base += 4)              // stage half=H/2
#pragma unroll
        for (int mm = 0; mm < 2; ++mm) {
            int a = base + mm, b = a + 2;
            float ur = xr[a] + xr[b], ui = xi[a] + xi[b];
            float dr = xr[a] - xr[b], di = xi[a] - xi[b];
            xr[a] = ur; xi[a] = ui;
            if (mm == 0) { xr[b] = dr * c2 - di * s2; xi[b] = dr * s2 + di * c2; }
            else         { xr[b] = dr * s2 + di * c2; xi[b] = di * s2 - dr * c2; }  // *T2*(-i)
        }
#pragma unroll
    for (int m = 0; m < 8; m += 2) {                     // stage half=H/4
        float ur = xr[m] + xr[m + 1], ui = xi[m] + xi[m + 1];
        float dr = xr[m] - xr[m + 1], di = xi[m] - xi[m + 1];
        xr[m] = ur; xi[m] = ui;
        xr[m + 1] = dr * c3 - di * s3; xi[m + 1] = dr * s3 + di * c3;
    }
#pragma unroll
    for (int m = 0; m < 8; ++m) A[ad[m]] = make_float2(xr[m], xi[m]);
}

// -------- single-group radix-8 inverse: stages (H, 2H, 4H) at base index i ------
template<int H>
__device__ __forceinline__ void inv8g1(float2* A, int i, float c, float s)
{
    float c2 = c * c - s * s, s2 = 2.f * c * s;          // T^2
    float c4 = c2 * c2 - s2 * s2, s4 = 2.f * c2 * s2;    // T^4
    float xr[8], xi[8]; int ad[8];
#pragma unroll
    for (int m = 0; m < 8; ++m) {
        ad[m] = IDX(i + m * H);
        float2 v = A[ad[m]];
        xr[m] = v.x; xi[m] = v.y;
    }
#pragma unroll
    for (int m = 0; m < 8; m += 2) {                     // half=H
        float tr = xr[m + 1] * c4 - xi[m + 1] * s4;
        float ti = xr[m + 1] * s4 + xi[m + 1] * c4;
        xr[m + 1] = xr[m] - tr; xi[m + 1] = xi[m] - ti;
        xr[m]     = xr[m] + tr; xi[m]     = xi[m] + ti;
    }
#pragma unroll
    for (int base = 0; base < 8; base += 4)              // half=2H
#pragma unroll
        for (int mm = 0; mm < 2; ++mm) {
            int a = base + mm, b = a + 2;
            float tr, ti;
            if (mm == 0) { tr = xr[b] * c2 - xi[b] * s2; ti = xr[b] * s2 + xi[b] * c2; }
            else         { tr = -(xr[b] * s2 + xi[b] * c2); ti = xr[b] * c2 - xi[b] * s2; }
            xr[b] = xr[a] - tr; xi[b] = xi[a] - ti;
            xr[a] = xr[a] + tr; xi[a] = xi[a] + ti;
        }
    const float r = 0.70710678118f;
    float t3c[4], t3s[4];
    t3c[0] = c;            t3s[0] = s;
    t3c[1] = r * (c - s);  t3s[1] = r * (c + s);
    t3c[2] = -s;           t3s[2] = c;
    t3c[3] = -r * (c + s); t3s[3] = r * (c - s);
#pragma unroll
    for (int m = 0; m < 4; ++m) {                        // half=4H
        float tr = xr[m + 4] * t3c[m] - xi[m + 4] * t3s[m];
        float ti = xr[m + 4] * t3s[m] + xi[m + 4] * t3c[m];
        xr[m + 4] = xr[m] - tr; xi[m + 4] = xi[m] - ti;
        xr[m]     = xr[m] + tr; xi[m]     = xi[m] + ti;
    }
#pragma unroll
    for (int m = 0; m < 8; ++m) A[ad[m]] = make_float2(xr[m], xi[m]);
}

// ---------------- forward FFT: barrier-reduced ----------------------------------
// pass1 (4096,2048,1024) is global; stages 512..16 + register tail (8,4,2,1) are
// chunk-local: wave w owns elements [1024w,1024w+1024) — intra-wave LDS ops are
// processed in order by the DS unit, so no barriers inside the fused region.
__device__ __forceinline__ void fft_fwd(float2* A, int t)
{
    {   // global pass: stages 4096,2048,1024 (groups j=t and j=t+512)
        float c1, s1;
        __sincosf((-PI_F / 4096.0f) * (float)t, &s1, &c1);
        fwd8g1<4096>(A, t, c1, s1);
        const float cR = 0.9238795325f, sR = -0.3826834324f;   // exp(-i*pi/8)
        fwd8g1<4096>(A, t + 512, c1 * cR - s1 * sR, s1 * cR + c1 * sR);
    }
    __syncthreads();
    {   // chunk-local: stages 512,256,128 | 64,32,16 | register tail 8,4,2,1
        int w = t >> 6, l = t & 63, base = w << 10;
        float ca, sa;                                    // T1 = exp(-i*pi*j/512)
        __sincosf((-PI_F / 512.0f) * (float)l, &sa, &ca);
        fwd8g1<512>(A, base + l, ca, sa);
        const float cR = 0.9238795325f, sR = -0.3826834324f;   // j -> j+64: *exp(-i*pi/8)
        fwd8g1<512>(A, base + 64 + l, ca * cR - sa * sR, sa * cR + ca * sR);

        float cb, sb;                                    // T1 = exp(-i*pi*j/64), j=l&15
        __sincosf((-PI_F / 64.0f) * (float)(l & 15), &sb, &cb);
        int i0 = base + ((l & ~15) << 3) + (l & 15);
        fwd8g1<64>(A, i0, cb, sb);
        fwd8g1<64>(A, i0 + 512, cb, sb);

        // register tail: halves 8,4,2,1 on 16 consecutive elements (R3 verbatim)
        int pb = IDX(16 * t);
        float fr[16], fi[16];
#pragma unroll
        for (int e = 0; e < 16; ++e) { float2 v = A[pb + e]; fr[e] = v.x; fi[e] = v.y; }
#pragma unroll
        for (int k = 0; k < 8; ++k) {
            float cs = C8[k], sn = S8n[k];
            float arr = fr[k], aii = fi[k], brr = fr[k + 8], bii = fi[k + 8];
            fr[k] = arr + brr; fi[k] = aii + bii;
            float dr = arr - brr, di = aii - bii;
            fr[k + 8] = dr * cs - di * sn; fi[k + 8] = dr * sn + di * cs;
        }
#pragma unroll
        for (int b0 = 0; b0 < 16; b0 += 8)
#pragma unroll
            for (int k = 0; k < 4; ++k) {
                float cs = C8[2 * k], sn = S8n[2 * k];
                int i1 = b0 + k, i2 = i1 + 4;
                float arr = fr[i1], aii = fi[i1], brr = fr[i2], bii = fi[i2];
                fr[i1] = arr + brr; fi[i1] = aii + bii;
                float dr = arr - brr, di = aii - bii;
                fr[i2] = dr * cs - di * sn; fi[i2] = dr * sn + di * cs;
            }
#pragma unroll
        for (int b0 = 0; b0 < 16; b0 += 4)
#pragma unroll
            for (int k = 0; k < 2; ++k) {
                float cs = C8[4 * k], sn = S8n[4 * k];
                int i1 = b0 + k, i2 = i1 + 2;
                float arr = fr[i1], aii = fi[i1], brr = fr[i2], bii = fi[i2];
                fr[i1] = arr + brr; fi[i1] = aii + bii;
                float dr = arr - brr, di = aii - bii;
                fr[i2] = dr * cs - di * sn; fi[i2] = dr * sn + di * cs;
            }
#pragma unroll
        for (int b0 = 0; b0 < 16; b0 += 2) {
            float arr = fr[b0], aii = fi[b0], brr = fr[b0 + 1], bii = fi[b0 + 1];
            fr[b0] = arr + brr; fi[b0] = aii + bii;
            fr[b0 + 1] = arr - brr; fi[b0 + 1] = aii - bii;
        }
#pragma unroll
        for (int e = 0; e < 16; ++e) A[pb + e] = make_float2(fr[e], fi[e]);
    }
    __syncthreads();
}

// ---------------- inverse FFT: barrier-reduced ----------------------------------
// head (1,2,4,8) + stages 16..512 are chunk-local (one wave per 1024-chunk);
// final pass (1024,2048,4096) is global.
__device__ __forceinline__ void fft_inv(float2* A, int t)
{
    {   // chunk-local: register head + stages 16,32,64 | 128,256,512
        int pb = IDX(16 * t);
        float fr[16], fi[16];
#pragma unroll
        for (int e = 0; e < 16; ++e) { float2 v = A[pb + e]; fr[e] = v.x; fi[e] = v.y; }
#pragma unroll
        for (int b0 = 0; b0 < 16; b0 += 2) {
            float arr = fr[b0], aii = fi[b0], brr = fr[b0 + 1], bii = fi[b0 + 1];
            fr[b0] = arr + brr; fi[b0] = aii + bii;
            fr[b0 + 1] = arr - brr; fi[b0 + 1] = aii - bii;
        }
#pragma unroll
        for (int b0 = 0; b0 < 16; b0 += 4)
#pragma unroll
            for (int k = 0; k < 2; ++k) {
                float cs = C8[4 * k], sn = S8p[4 * k];
                int i1 = b0 + k, i2 = i1 + 2;
                float arr = fr[i1], aii = fi[i1], brr = fr[i2], bii = fi[i2];
                float tr = brr * cs - bii * sn, ti = brr * sn + bii * cs;
                fr[i1] = arr + tr; fi[i1] = aii + ti;
                fr[i2] = arr - tr; fi[i2] = aii - ti;
            }
#pragma unroll
        for (int b0 = 0; b0 < 16; b0 += 8)
#pragma unroll
            for (int k = 0; k < 4; ++k) {
                float cs = C8[2 * k], sn = S8p[2 * k];
                int i1 = b0 + k, i2 = i1 + 4;
                float arr = fr[i1], aii = fi[i1], brr = fr[i2], bii = fi[i2];
                float tr = brr * cs - bii * sn, ti = brr * sn + bii * cs;
                fr[i1] = arr + tr; fi[i1] = aii + ti;
                fr[i2] = arr - tr; fi[i2] = aii - ti;
            }
#pragma unroll
        for (int k = 0; k < 8; ++k) {
            float cs = C8[k], sn = S8p[k];
            float arr = fr[k], aii = fi[k], brr = fr[k + 8], bii = fi[k + 8];
            float tr = brr * cs - bii * sn, ti = brr * sn + bii * cs;
            fr[k] = arr + tr; fi[k] = aii + ti;
            fr[k + 8] = arr - tr; fi[k + 8] = aii - ti;
        }
#pragma unroll
        for (int e = 0; e < 16; ++e) A[pb + e] = make_float2(fr[e], fi[e]);

        int w = t >> 6, l = t & 63, base = w << 10;
        float ca, sa;                                    // T = exp(i*pi*j/64), j=l&15
        __sincosf((PI_F / 64.0f) * (float)(l & 15), &sa, &ca);
        int i0 = base + ((l & ~15) << 3) + (l & 15);
        inv8g1<16>(A, i0, ca, sa);
        inv8g1<16>(A, i0 + 512, ca, sa);

        float cb, sb;                                    // T = exp(i*pi*j/512), j=l
        __sincosf((PI_F / 512.0f) * (float)l, &sb, &cb);
        inv8g1<128>(A, base + l, cb, sb);
        const float cR = 0.9238795325f, sR = 0.3826834324f;    // j -> j+64: *exp(+i*pi/8)
        inv8g1<128>(A, base + 64 + l, cb * cR - sb * sR, sb * cR + cb * sR);
    }
    __syncthreads();
    {   // global pass: stages 1024,2048,4096 (groups j=t and j=t+512)
        float c1, s1;
        __sincosf((PI_F / 4096.0f) * (float)t, &s1, &c1);
        inv8g1<1024>(A, t, c1, s1);
        const float cR = 0.9238795325f, sR = 0.3826834324f;    // exp(+i*pi/8)
        inv8g1<1024>(A, t + 512, c1 * cR - s1 * sR, s1 * cR + c1 * sR);
    }
    __syncthreads();
}

// ---------------- kf: K_f[d] = rfft(k_d, 16384), fp16-packed -------------------
// kb0/kb1: destination row bases. If kb1 == kb0 (workspace mode) the duplicate
// write is skipped (conv reads the single copy for both batches).
__global__ __launch_bounds__(512, 4) void kf_kernel(
    float* outk, float* kb0, float* kb1)
{
    __shared__ float2 A[LDS_SZ];
    int t = threadIdx.x, d = blockIdx.x;
    const float* kp = outk + (size_t)d * SEQ;
    for (int n = t; n < 4096; n += 512) {
        A[IDX(n)] = ((const float2*)kp)[n];
    }
    for (int n = 4096 + t; n < M; n += 512) A[IDX(n)] = make_float2(0.f, 0.f);
    __syncthreads();
    fft_fwd(A, t);

    __half2* P0 = (__half2*)(kb0 + (size_t)d * SEQ);
    __half2* P1 = (__half2*)(kb1 + (size_t)d * SEQ);
    bool dup = (kb1 != kb0);
    float cs, sn;
    __sincosf(-PI_F * (float)t * (1.0f / 8192.0f), &sn, &cs);
    const float cRo = 0.9807852804f, sRo = -0.1950903220f;   // exp(-i*pi/16)
    for (int j = t; j <= 4096; j += 512) {
        int jm = (M - j) & (M - 1);
        int p0 = rev13(j), p1 = rev13(jm);
        float2 z1 = A[IDX(p0)], z2 = A[IDX(p1)];
        float Ar_ = 0.5f * (z1.x + z2.x), Ai_ = 0.5f * (z1.y - z2.y);
        float Br_ = 0.5f * (z1.y + z2.y), Bi_ = 0.5f * (z2.x - z1.x);
        float wbr = cs * Br_ - sn * Bi_, wbi = cs * Bi_ + sn * Br_;
        float K1r = Ar_ + wbr, K1i = Ai_ + wbi;
        float K2r = Ar_ - wbr, K2i = -(Ai_ - wbi);
        if (j == 0) {
            __half2 v = __floats2half2_rn(K1r, K2r);
            P0[0] = v; if (dup) P1[0] = v;
        } else {
            __half2 v1 = __floats2half2_rn(K1r, K1i);
            P0[j] = v1; if (dup) P1[j] = v1;
            if (j != 4096) {
                __half2 v2 = __floats2half2_rn(K2r, K2i);
                P0[M - j] = v2; if (dup) P1[M - j] = v2;
            }
        }
        float cn = cs * cRo - sn * sRo; sn = sn * cRo + cs * sRo; cs = cn;
    }
}

// ---------------- conv: block (d,b): y = irfft(rfft(x)*(K + bias_d))[:8192] ------
// bias fold: y + x*bias_d == irfft(U_f * (K_f + bias_d))[:8192] (bias*delta0 has a
// flat real spectrum; irfft(rfft(x,2L),2L)[:L]==x exactly for zero-padded x).
// K row = kbase + (b*kstride + d)*SEQ; kstride=0 in workspace (shared-K) mode.
__global__ __launch_bounds__(512, 4) void conv_kernel(
    const float* __restrict__ x, const float* __restrict__ bias,
    float* outk, const float* __restrict__ kbase, int kstride)
{
    __shared__ float2 A[LDS_SZ];
    int t = threadIdx.x, d = blockIdx.x, b = blockIdx.y;
    const float* xp = x + ((size_t)(b * D_MODEL + d)) * SEQ;
    float bd = bias[d];

#pragma unroll
    for (int idx = 0; idx < 8; ++idx) {
        int n = t + (idx << 9);
        A[IDX(n)] = ((const float2*)xp)[n];
    }
    for (int n = 4096 + t; n < M; n += 512) A[IDX(n)] = make_float2(0.f, 0.f);
    __syncthreads();
    fft_fwd(A, t);

    const __half2* P = (const __half2*)(kbase + (size_t)(b * kstride + d) * SEQ);
    float cs, sn;
    __sincosf(-PI_F * (float)t * (1.0f / 8192.0f), &sn, &cs);
    const float cRo = 0.9807852804f, sRo = -0.1950903220f;   // exp(-i*pi/16)
    for (int j = t; j <= 4096; j += 512) {
        int jm = (M - j) & (M - 1);
        int p0 = rev13(j), p1 = rev13(jm);
        int q0 = IDX(p0), q1 = IDX(p1);
        float2 z1 = A[q0], z2 = A[q1];
        float Ar_ = 0.5f * (z1.x + z2.x), Ai_ = 0.5f * (z1.y - z2.y);
        float Br_ = 0.5f * (z1.y + z2.y), Bi_ = 0.5f * (z2.x - z1.x);
        float wbr = cs * Br_ - sn * Bi_, wbi = cs * Bi_ + sn * Br_;
        float U1r = Ar_ + wbr, U1i = Ai_ + wbi;
        float U2r = Ar_ - wbr, U2i = -(Ai_ - wbi);
        float K1r, K1i, K2r, K2i;
        if (j == 0) {
            __half2 v = P[0];
            K1r = __low2float(v) + bd;  K1i = 0.f;
            K2r = __high2float(v) + bd; K2i = 0.f;
        } else {
            __half2 v1 = P[j];
            __half2 v2 = P[M - j];
            K1r = __low2float(v1) + bd; K1i = __high2float(v1);
            K2r = __low2float(v2) + bd; K2i = __high2float(v2);
        }
        float P1r = U1r * K1r - U1i * K1i, P1i = U1r * K1i + U1i * K1r;
        float P2r = U2r * K2r - U2i * K2i, P2i = U2r * K2i + U2i * K2r;
        float Er = 0.5f * (P1r + P2r), Ei = 0.5f * (P1i - P2i);
        float Or = 0.5f * (P1r - P2r), Oi = 0.5f * (P1i + P2i);
        float G = cs * Oi - sn * Or;
        float H = cs * Or + sn * Oi;
        A[q0] = make_float2(Er - G, Ei + H);
        if (j != 0) A[q1] = make_float2(Er + G, -Ei + H);
        float cn = cs * cRo - sn * sRo; sn = sn * cRo + cs * sRo; cs = cn;
    }
    __syncthreads();
    fft_inv(A, t);

    const float invM = 1.0f / 8192.0f;
    float* op = outk + ((size_t)(b * D_MODEL + d)) * SEQ;
#pragma unroll
    for (int idx = 0; idx < 8; ++idx) {
        int n = t + (idx << 9);
        float2 v = A[IDX(n)];
        float2 ov;
        ov.x = v.x * invM;
        ov.y = v.y * invM;
        ((float2*)op)[n] = ov;
    }
}

extern "C" void kernel_launch(void* const* d_in, const int* in_sizes, int n_in,
                              void* d_out, int out_size, void* d_ws, size_t ws_size,
                              hipStream_t stream)
{
    (void)in_sizes; (void)n_in; (void)out_size;
    const float* x      = (const float*)d_in[0];
    // d_in[1] = L (always 8192, hardcoded)
    const float* z      = (const float*)d_in[2];
    const float* tvec   = (const float*)d_in[3];
    const float* freq   = (const float*)d_in[4];
    const float* W1     = (const float*)d_in[5];
    const float* b1     = (const float*)d_in[6];
    const float* W2     = (const float*)d_in[7];
    const float* b2     = (const float*)d_in[8];
    const float* W3     = (const float*)d_in[9];
    const float* b3     = (const float*)d_in[10];
    const float* Wout   = (const float*)d_in[11];
    const float* deltas = (const float*)d_in[12];
    const float* bias   = (const float*)d_in[13];
    float* out = (float*)d_out;

    // staging inside d_out (12,582,912 floats):
    //   h3T (64 x 8192, transposed) -> last 64 rows of b=1 half (dead after filt)
    //   k  -> rows (0,d)   (consumed by kf block d)
    //   K packed fp16: in workspace (single copy, shared by both batches) when
    //   ws_size permits; else duplicated into rows (0,d) and (1,d) of d_out.
    float* h3T = out + ((size_t)(2 * D_MODEL - 64) * SEQ);
    float* k   = out;

    const size_t kbytes = (size_t)D_MODEL * SEQ * sizeof(float);  // 25.2 MB packed K
    bool usews = (d_ws != nullptr) && (ws_size >= kbytes);
    float* kws = (float*)d_ws;
    float* kb0 = usews ? kws : out;
    float* kb1 = usews ? kws : out + (size_t)D_MODEL * SEQ;
    const float* kbase = usews ? kws : out;
    int kstride = usews ? 0 : D_MODEL;

    hipLaunchKernelGGL(mlp_kernel, dim3(SEQ / 64), dim3(256), 0, stream,
                       z, freq, W1, b1, W2, b2, W3, b3, h3T);
    hipLaunchKernelGGL(filt_kernel, dim3(SEQ / 128, D_MODEL / 64), dim3(256), 0, stream,
                       h3T, Wout, tvec, deltas, k);
    hipLaunchKernelGGL(kf_kernel, dim3(D_MODEL), dim3(512), 0, stream,
                       out, kb0, kb1);
    hipLaunchKernelGGL(conv_kernel, dim3(D_MODEL, BATCH), dim3(512), 0, stream,
                       x, bias, out, kbase, kstride);
}

// Round 12
// 225.793 us; speedup vs baseline: 1.1134x; 1.0209x over previous
//
#include <hip/hip_runtime.h>
#include <hip/hip_fp16.h>
#include <math.h>

#define D_MODEL 768
#define EMB 33
#define ORDER 64
#define SEQ 8192
#define BATCH 2
#define M 8192      // half-size complex FFT length (N = 16384 real)

#define PI_F 3.14159265358979323846f

// padded LDS index in COMPLEX units: +1 per 16, +1 per 128
#define IDX(a) ((a) + ((a) >> 4) + ((a) >> 7))
#define LDS_SZ 8768      // complex slots; 8768*8B = 70,144 B -> 2 blocks/CU

__device__ __forceinline__ int rev13(int x) { return (int)(__brev((unsigned)x) >> 19); }

// twiddle constants for register tail/head (angle pi*k/8)
__device__ __constant__ float C8[8] = {
    1.f, 0.9238795325f, 0.7071067812f, 0.3826834324f,
    0.f, -0.3826834324f, -0.7071067812f, -0.9238795325f };
__device__ __constant__ float S8n[8] = {   // -sin(pi k/8)  (forward DIF)
    0.f, -0.3826834324f, -0.7071067812f, -0.9238795325f,
    -1.f, -0.9238795325f, -0.7071067812f, -0.3826834324f };
__device__ __constant__ float S8p[8] = {   // +sin(pi k/8)  (inverse DIT)
    0.f, 0.3826834324f, 0.7071067812f, 0.9238795325f,
    1.f, 0.9238795325f, 0.7071067812f, 0.3826834324f };

// ---------------- MLP: h3T[o][l] = sin-MLP(z[l])[o], register-tiled ----------
// 32 l per block -> 256 blocks (1/CU, full CU coverage; old 64-l version had
// 128 blocks x 63KB LDS = half the GPU idle). Thread tile = 2l x 4o.
// h1/h2 row stride 42 (42 mod 32 = 10; 4-row stride = 168 = 8 mod 32) keeps the
// 4 oy-groups' float2 writes on distinct banks.
__global__ __launch_bounds__(256) void mlp_kernel(
    const float* __restrict__ z, const float* __restrict__ freq,
    const float* __restrict__ W1, const float* __restrict__ b1,
    const float* __restrict__ W2, const float* __restrict__ b2,
    const float* __restrict__ W3, const float* __restrict__ b3,
    float* __restrict__ h3T)
{
    __shared__ float zt[33 * 40];    // zt[e][l], rows of 40
    __shared__ float h1[64 * 42];    // h[o][l], rows of 42
    __shared__ float h2[64 * 42];
    __shared__ float Wb[64 * 68];    // W[e][o], rows of 68 (272B, 16B-aligned)
    __shared__ float sfr[64], sb[64];
    int t = threadIdx.x;
    int l0 = blockIdx.x * 32;

    for (int i = t; i < 32 * 33; i += 256) {
        int l = i / 33, e = i - l * 33;
        zt[e * 40 + l] = z[(size_t)(l0 + l) * 33 + e];
    }
    for (int i = t; i < 64 * 33; i += 256) {
        int o = i / 33, e = i - o * 33;
        Wb[e * 68 + o] = W1[i];
    }
    if (t < 64) { sfr[t] = freq[t]; sb[t] = b1[t]; }
    __syncthreads();

    int lx = t & 15, oy = t >> 4;           // 16 lx * 2l = 32 l; 16 oy * 4o = 64 o
    float fr4[4], bi4[4], acc[2][4];
#pragma unroll
    for (int i = 0; i < 4; ++i) { fr4[i] = sfr[4 * oy + i]; bi4[i] = sb[4 * oy + i]; }
#pragma unroll
    for (int c = 0; c < 2; ++c)
#pragma unroll
        for (int i = 0; i < 4; ++i) acc[c][i] = bi4[i];
    for (int e = 0; e < 33; ++e) {
        float2 hv = *(const float2*)&zt[e * 40 + 2 * lx];
        float4 wv = *(const float4*)&Wb[e * 68 + 4 * oy];
        float h[2] = {hv.x, hv.y}, w[4] = {wv.x, wv.y, wv.z, wv.w};
#pragma unroll
        for (int c = 0; c < 2; ++c)
#pragma unroll
            for (int i = 0; i < 4; ++i) acc[c][i] = fmaf(h[c], w[i], acc[c][i]);
    }
#pragma unroll
    for (int i = 0; i < 4; ++i) {
        float2 v = make_float2(__sinf(fr4[i] * acc[0][i]), __sinf(fr4[i] * acc[1][i]));
        *(float2*)&h1[(4 * oy + i) * 42 + 2 * lx] = v;
    }
    __syncthreads();

    for (int i = t; i < 4096; i += 256) {    // W2[o][q] -> Wb[q][o]
        int o = i >> 6, q = i & 63;
        Wb[q * 68 + o] = W2[i];
    }
    if (t < 64) sb[t] = b2[t];
    __syncthreads();
#pragma unroll
    for (int i = 0; i < 4; ++i) bi4[i] = sb[4 * oy + i];
#pragma unroll
    for (int c = 0; c < 2; ++c)
#pragma unroll
        for (int i = 0; i < 4; ++i) acc[c][i] = bi4[i];
    for (int q = 0; q < 64; ++q) {
        float2 hv = *(const float2*)&h1[q * 42 + 2 * lx];
        float4 wv = *(const float4*)&Wb[q * 68 + 4 * oy];
        float h[2] = {hv.x, hv.y}, w[4] = {wv.x, wv.y, wv.z, wv.w};
#pragma unroll
        for (int c = 0; c < 2; ++c)
#pragma unroll
            for (int i = 0; i < 4; ++i) acc[c][i] = fmaf(h[c], w[i], acc[c][i]);
    }
#pragma unroll
    for (int i = 0; i < 4; ++i) {
        float2 v = make_float2(__sinf(fr4[i] * acc[0][i]), __sinf(fr4[i] * acc[1][i]));
        *(float2*)&h2[(4 * oy + i) * 42 + 2 * lx] = v;
    }
    __syncthreads();

    for (int i = t; i < 4096; i += 256) {    // W3[o][q] -> Wb[q][o]
        int o = i >> 6, q = i & 63;
        Wb[q * 68 + o] = W3[i];
    }
    if (t < 64) sb[t] = b3[t];
    __syncthreads();
#pragma unroll
    for (int i = 0; i < 4; ++i) bi4[i] = sb[4 * oy + i];
#pragma unroll
    for (int c = 0; c < 2; ++c)
#pragma unroll
        for (int i = 0; i < 4; ++i) acc[c][i] = bi4[i];
    for (int q = 0; q < 64; ++q) {
        float2 hv = *(const float2*)&h2[q * 42 + 2 * lx];
        float4 wv = *(const float4*)&Wb[q * 68 + 4 * oy];
        float h[2] = {hv.x, hv.y}, w[4] = {wv.x, wv.y, wv.z, wv.w};
#pragma unroll
        for (int c = 0; c < 2; ++c)
#pragma unroll
            for (int i = 0; i < 4; ++i) acc[c][i] = fmaf(h[c], w[i], acc[c][i]);
    }
#pragma unroll
    for (int i = 0; i < 4; ++i) {
        float2 v = make_float2(__sinf(fr4[i] * acc[0][i]), __sinf(fr4[i] * acc[1][i]));
        *(float2*)&h3T[(size_t)(4 * oy + i) * SEQ + l0 + 2 * lx] = v;
    }
}

// ------- filter: k[d][l] = (h3[l]·Wout[d]) * exp(-t[l]*|delta[d]|), tiled -------
__global__ __launch_bounds__(256) void filt_kernel(
    const float* __restrict__ h3T, const float* __restrict__ Wout,
    const float* __restrict__ tvec, const float* __restrict__ deltas,
    float* __restrict__ kout)
{
    __shared__ float ht[64 * 132];   // ht[kk][l], rows 132 (528B, 16B-aligned)
    __shared__ float wt[64 * 68];    // wt[kk][dd], rows 68
    int t = threadIdx.x;
    int l0 = blockIdx.x * 128, d0 = blockIdx.y * 64;

    for (int i = t; i < 64 * 128; i += 256) {
        int o = i >> 7, l = i & 127;
        ht[o * 132 + l] = h3T[(size_t)o * SEQ + l0 + l];
    }
    for (int i = t; i < 4096; i += 256) {    // Wout[d][kk] -> wt[kk][dd]
        int dd = i >> 6, kk = i & 63;
        wt[kk * 68 + dd] = Wout[(size_t)(d0 + dd) * 64 + kk];
    }
    __syncthreads();

    int lx = t & 31, dy = t >> 5;            // 32 lx * 4l = 128; 8 dy * 8d = 64
    float acc[4][8];
#pragma unroll
    for (int c = 0; c < 4; ++c)
#pragma unroll
        for (int i = 0; i < 8; ++i) acc[c][i] = 0.f;
    for (int kk = 0; kk < 64; ++kk) {
        float4 hv = *(const float4*)&ht[kk * 132 + 4 * lx];
        float4 w0 = *(const float4*)&wt[kk * 68 + 8 * dy];
        float4 w1 = *(const float4*)&wt[kk * 68 + 8 * dy + 4];
        float h[4] = {hv.x, hv.y, hv.z, hv.w};
        float w[8] = {w0.x, w0.y, w0.z, w0.w, w1.x, w1.y, w1.z, w1.w};
#pragma unroll
        for (int c = 0; c < 4; ++c)
#pragma unroll
            for (int i = 0; i < 8; ++i) acc[c][i] = fmaf(h[c], w[i], acc[c][i]);
    }

    float4 tl4 = *(const float4*)&tvec[l0 + 4 * lx];
    float tl[4] = {tl4.x, tl4.y, tl4.z, tl4.w};
    float del[8];
#pragma unroll
    for (int i = 0; i < 8; ++i) del[i] = fabsf(deltas[d0 + 8 * dy + i]);
#pragma unroll
    for (int i = 0; i < 8; ++i) {
        int d = d0 + 8 * dy + i;
        float4 v = make_float4(acc[0][i] * __expf(-tl[0] * del[i]),
                               acc[1][i] * __expf(-tl[1] * del[i]),
                               acc[2][i] * __expf(-tl[2] * del[i]),
                               acc[3][i] * __expf(-tl[3] * del[i]));
        *(float4*)&kout[(size_t)d * SEQ + l0 + 4 * lx] = v;
    }
}

// -------- single-group radix-8 forward: stages (H, H/2, H/4) at base index i ----
template<int H>
__device__ __forceinline__ void fwd8g1(float2* A, int i, float c1, float s1)
{
    constexpr int H4 = H / 4;
    float c2 = c1 * c1 - s1 * s1, s2 = 2.f * c1 * s1;   // T1^2
    float c3 = c2 * c2 - s2 * s2, s3 = 2.f * c2 * s2;   // T1^4
    float xr[8], xi[8];
    int ad[8];
#pragma unroll
    for (int m = 0; m < 8; ++m) {
        ad[m] = IDX(i + m * H4);
        float2 v = A[ad[m]];
        xr[m] = v.x; xi[m] = v.y;
    }
    const float r = 0.70710678118f;
    float twc[4], tws[4];                                // T1 * W8^m
    twc[0] = c1;            tws[0] = s1;
    twc[1] = r * (c1 + s1); tws[1] = r * (s1 - c1);
    twc[2] = s1;            tws[2] = -c1;
    twc[3] = r * (s1 - c1); tws[3] = -r * (c1 + s1);
#pragma unroll
    for (int m = 0; m < 4; ++m) {                        // stage half=H
        float ur = xr[m] + xr[m + 4], ui = xi[m] + xi[m + 4];
        float dr = xr[m] - xr[m + 4], di = xi[m] - xi[m + 4];
        xr[m] = ur; xi[m] = ui;
        xr[m + 4] = dr * twc[m] - di * tws[m];
        xi[m + 4] = dr * tws[m] + di * twc[m];
    }
#pragma unroll
    for (int base = 0; base < 8; base += 4)              // stage half=H/2
#pragma unroll
        for (int mm = 0; mm < 2; ++mm) {
            int a = base + mm, b = a + 2;
            float ur = xr[a] + xr[b], ui = xi[a] + xi[b];
            float dr = xr[a] - xr[b], di = xi[a] - xi[b];
            xr[a] = ur; xi[a] = ui;
            if (mm == 0) { xr[b] = dr * c2 - di * s2; xi[b] = dr * s2 + di * c2; }
            else         { xr[b] = dr * s2 + di * c2; xi[b] = di * s2 - dr * c2; }  // *T2*(-i)
        }
#pragma unroll
    for (int m = 0; m < 8; m += 2) {                     // stage half=H/4
        float ur = xr[m] + xr[m + 1], ui = xi[m] + xi[m + 1];
        float dr = xr[m] - xr[m + 1], di = xi[m] - xi[m + 1];
        xr[m] = ur; xi[m] = ui;
        xr[m + 1] = dr * c3 - di * s3; xi[m + 1] = dr * s3 + di * c3;
    }
#pragma unroll
    for (int m = 0; m < 8; ++m) A[ad[m]] = make_float2(xr[m], xi[m]);
}

// -------- single-group radix-8 inverse: stages (H, 2H, 4H) at base index i ------
template<int H>
__device__ __forceinline__ void inv8g1(float2* A, int i, float c, float s)
{
    float c2 = c * c - s * s, s2 = 2.f * c * s;          // T^2
    float c4 = c2 * c2 - s2 * s2, s4 = 2.f * c2 * s2;    // T^4
    float xr[8], xi[8]; int ad[8];
#pragma unroll
    for (int m = 0; m < 8; ++m) {
        ad[m] = IDX(i + m * H);
        float2 v = A[ad[m]];
        xr[m] = v.x; xi[m] = v.y;
    }
#pragma unroll
    for (int m = 0; m < 8; m += 2) {                     // half=H
        float tr = xr[m + 1] * c4 - xi[m + 1] * s4;
        float ti = xr[m + 1] * s4 + xi[m + 1] * c4;
        xr[m + 1] = xr[m] - tr; xi[m + 1] = xi[m] - ti;
        xr[m]     = xr[m] + tr; xi[m]     = xi[m] + ti;
    }
#pragma unroll
    for (int base = 0; base < 8; base += 4)              // half=2H
#pragma unroll
        for (int mm = 0; mm < 2; ++mm) {
            int a = base + mm, b = a + 2;
            float tr, ti;
            if (mm == 0) { tr = xr[b] * c2 - xi[b] * s2; ti = xr[b] * s2 + xi[b] * c2; }
            else         { tr = -(xr[b] * s2 + xi[b] * c2); ti = xr[b] * c2 - xi[b] * s2; }
            xr[b] = xr[a] - tr; xi[b] = xi[a] - ti;
            xr[a] = xr[a] + tr; xi[a] = xi[a] + ti;
        }
    const float r = 0.70710678118f;
    float t3c[4], t3s[4];
    t3c[0] = c;            t3s[0] = s;
    t3c[1] = r * (c - s);  t3s[1] = r * (c + s);
    t3c[2] = -s;           t3s[2] = c;
    t3c[3] = -r * (c + s); t3s[3] = r * (c - s);
#pragma unroll
    for (int m = 0; m < 4; ++m) {                        // half=4H
        float tr = xr[m + 4] * t3c[m] - xi[m + 4] * t3s[m];
        float ti = xr[m + 4] * t3s[m] + xi[m + 4] * t3c[m];
        xr[m + 4] = xr[m] - tr; xi[m + 4] = xi[m] - ti;
        xr[m]     = xr[m] + tr; xi[m]     = xi[m] + ti;
    }
#pragma unroll
    for (int m = 0; m < 8; ++m) A[ad[m]] = make_float2(xr[m], xi[m]);
}

// ---------------- forward FFT: barrier-reduced ----------------------------------
// pass1 (4096,2048,1024) is global; stages 512..16 + register tail (8,4,2,1) are
// chunk-local: wave w owns elements [1024w,1024w+1024) — intra-wave LDS ops are
// processed in order by the DS unit, so no barriers inside the fused region.
__device__ __forceinline__ void fft_fwd(float2* A, int t)
{
    {   // global pass: stages 4096,2048,1024 (groups j=t and j=t+512)
        float c1, s1;
        __sincosf((-PI_F / 4096.0f) * (float)t, &s1, &c1);
        fwd8g1<4096>(A, t, c1, s1);
        const float cR = 0.9238795325f, sR = -0.3826834324f;   // exp(-i*pi/8)
        fwd8g1<4096>(A, t + 512, c1 * cR - s1 * sR, s1 * cR + c1 * sR);
    }
    __syncthreads();
    {   // chunk-local: stages 512,256,128 | 64,32,16 | register tail 8,4,2,1
        int w = t >> 6, l = t & 63, base = w << 10;
        float ca, sa;                                    // T1 = exp(-i*pi*j/512)
        __sincosf((-PI_F / 512.0f) * (float)l, &sa, &ca);
        fwd8g1<512>(A, base + l, ca, sa);
        const float cR = 0.9238795325f, sR = -0.3826834324f;   // j -> j+64: *exp(-i*pi/8)
        fwd8g1<512>(A, base + 64 + l, ca * cR - sa * sR, sa * cR + ca * sR);

        float cb, sb;                                    // T1 = exp(-i*pi*j/64), j=l&15
        __sincosf((-PI_F / 64.0f) * (float)(l & 15), &sb, &cb);
        int i0 = base + ((l & ~15) << 3) + (l & 15);
        fwd8g1<64>(A, i0, cb, sb);
        fwd8g1<64>(A, i0 + 512, cb, sb);

        // register tail: halves 8,4,2,1 on 16 consecutive elements (R3 verbatim)
        int pb = IDX(16 * t);
        float fr[16], fi[16];
#pragma unroll
        for (int e = 0; e < 16; ++e) { float2 v = A[pb + e]; fr[e] = v.x; fi[e] = v.y; }
#pragma unroll
        for (int k = 0; k < 8; ++k) {
            float cs = C8[k], sn = S8n[k];
            float arr = fr[k], aii = fi[k], brr = fr[k + 8], bii = fi[k + 8];
            fr[k] = arr + brr; fi[k] = aii + bii;
            float dr = arr - brr, di = aii - bii;
            fr[k + 8] = dr * cs - di * sn; fi[k + 8] = dr * sn + di * cs;
        }
#pragma unroll
        for (int b0 = 0; b0 < 16; b0 += 8)
#pragma unroll
            for (int k = 0; k < 4; ++k) {
                float cs = C8[2 * k], sn = S8n[2 * k];
                int i1 = b0 + k, i2 = i1 + 4;
                float arr = fr[i1], aii = fi[i1], brr = fr[i2], bii = fi[i2];
                fr[i1] = arr + brr; fi[i1] = aii + bii;
                float dr = arr - brr, di = aii - bii;
                fr[i2] = dr * cs - di * sn; fi[i2] = dr * sn + di * cs;
            }
#pragma unroll
        for (int b0 = 0; b0 < 16; b0 += 4)
#pragma unroll
            for (int k = 0; k < 2; ++k) {
                float cs = C8[4 * k], sn = S8n[4 * k];
                int i1 = b0 + k, i2 = i1 + 2;
                float arr = fr[i1], aii = fi[i1], brr = fr[i2], bii = fi[i2];
                fr[i1] = arr + brr; fi[i1] = aii + bii;
                float dr = arr - brr, di = aii - bii;
                fr[i2] = dr * cs - di * sn; fi[i2] = dr * sn + di * cs;
            }
#pragma unroll
        for (int b0 = 0; b0 < 16; b0 += 2) {
            float arr = fr[b0], aii = fi[b0], brr = fr[b0 + 1], bii = fi[b0 + 1];
            fr[b0] = arr + brr; fi[b0] = aii + bii;
            fr[b0 + 1] = arr - brr; fi[b0 + 1] = aii - bii;
        }
#pragma unroll
        for (int e = 0; e < 16; ++e) A[pb + e] = make_float2(fr[e], fi[e]);
    }
    __syncthreads();
}

// ---------------- inverse FFT: barrier-reduced ----------------------------------
// head (1,2,4,8) + stages 16..512 are chunk-local (one wave per 1024-chunk);
// final pass (1024,2048,4096) is global.
__device__ __forceinline__ void fft_inv(float2* A, int t)
{
    {   // chunk-local: register head + stages 16,32,64 | 128,256,512
        int pb = IDX(16 * t);
        float fr[16], fi[16];
#pragma unroll
        for (int e = 0; e < 16; ++e) { float2 v = A[pb + e]; fr[e] = v.x; fi[e] = v.y; }
#pragma unroll
        for (int b0 = 0; b0 < 16; b0 += 2) {
            float arr = fr[b0], aii = fi[b0], brr = fr[b0 + 1], bii = fi[b0 + 1];
            fr[b0] = arr + brr; fi[b0] = aii + bii;
            fr[b0 + 1] = arr - brr; fi[b0 + 1] = aii - bii;
        }
#pragma unroll
        for (int b0 = 0; b0 < 16; b0 += 4)
#pragma unroll
            for (int k = 0; k < 2; ++k) {
                float cs = C8[4 * k], sn = S8p[4 * k];
                int i1 = b0 + k, i2 = i1 + 2;
                float arr = fr[i1], aii = fi[i1], brr = fr[i2], bii = fi[i2];
                float tr = brr * cs - bii * sn, ti = brr * sn + bii * cs;
                fr[i1] = arr + tr; fi[i1] = aii + ti;
                fr[i2] = arr - tr; fi[i2] = aii - ti;
            }
#pragma unroll
        for (int b0 = 0; b0 < 16; b0 += 8)
#pragma unroll
            for (int k = 0; k < 4; ++k) {
                float cs = C8[2 * k], sn = S8p[2 * k];
                int i1 = b0 + k, i2 = i1 + 4;
                float arr = fr[i1], aii = fi[i1], brr = fr[i2], bii = fi[i2];
                float tr = brr * cs - bii * sn, ti = brr * sn + bii * cs;
                fr[i1] = arr + tr; fi[i1] = aii + ti;
                fr[i2] = arr - tr; fi[i2] = aii - ti;
            }
#pragma unroll
        for (int k = 0; k < 8; ++k) {
            float cs = C8[k], sn = S8p[k];
            float arr = fr[k], aii = fi[k], brr = fr[k + 8], bii = fi[k + 8];
            float tr = brr * cs - bii * sn, ti = brr * sn + bii * cs;
            fr[k] = arr + tr; fi[k] = aii + ti;
            fr[k + 8] = arr - tr; fi[k + 8] = aii - ti;
        }
#pragma unroll
        for (int e = 0; e < 16; ++e) A[pb + e] = make_float2(fr[e], fi[e]);

        int w = t >> 6, l = t & 63, base = w << 10;
        float ca, sa;                                    // T = exp(i*pi*j/64), j=l&15
        __sincosf((PI_F / 64.0f) * (float)(l & 15), &sa, &ca);
        int i0 = base + ((l & ~15) << 3) + (l & 15);
        inv8g1<16>(A, i0, ca, sa);
        inv8g1<16>(A, i0 + 512, ca, sa);

        float cb, sb;                                    // T = exp(i*pi*j/512), j=l
        __sincosf((PI_F / 512.0f) * (float)l, &sb, &cb);
        inv8g1<128>(A, base + l, cb, sb);
        const float cR = 0.9238795325f, sR = 0.3826834324f;    // j -> j+64: *exp(+i*pi/8)
        inv8g1<128>(A, base + 64 + l, cb * cR - sb * sR, sb * cR + cb * sR);
    }
    __syncthreads();
    {   // global pass: stages 1024,2048,4096 (groups j=t and j=t+512)
        float c1, s1;
        __sincosf((PI_F / 4096.0f) * (float)t, &s1, &c1);
        inv8g1<1024>(A, t, c1, s1);
        const float cR = 0.9238795325f, sR = 0.3826834324f;    // exp(+i*pi/8)
        inv8g1<1024>(A, t + 512, c1 * cR - s1 * sR, s1 * cR + c1 * sR);
    }
    __syncthreads();
}

// ---------------- kf: K_f[d] = rfft(k_d, 16384), fp16-packed -------------------
// kb0/kb1: destination row bases. If kb1 == kb0 (workspace mode) the duplicate
// write is skipped (conv reads the single copy for both batches).
__global__ __launch_bounds__(512, 4) void kf_kernel(
    float* outk, float* kb0, float* kb1)
{
    __shared__ float2 A[LDS_SZ];
    int t = threadIdx.x, d = blockIdx.x;
    const float* kp = outk + (size_t)d * SEQ;
    for (int n = t; n < 4096; n += 512) {
        A[IDX(n)] = ((const float2*)kp)[n];
    }
    for (int n = 4096 + t; n < M; n += 512) A[IDX(n)] = make_float2(0.f, 0.f);
    __syncthreads();
    fft_fwd(A, t);

    __half2* P0 = (__half2*)(kb0 + (size_t)d * SEQ);
    __half2* P1 = (__half2*)(kb1 + (size_t)d * SEQ);
    bool dup = (kb1 != kb0);
    float cs, sn;
    __sincosf(-PI_F * (float)t * (1.0f / 8192.0f), &sn, &cs);
    const float cRo = 0.9807852804f, sRo = -0.1950903220f;   // exp(-i*pi/16)
    for (int j = t; j <= 4096; j += 512) {
        int jm = (M - j) & (M - 1);
        int p0 = rev13(j), p1 = rev13(jm);
        float2 z1 = A[IDX(p0)], z2 = A[IDX(p1)];
        float Ar_ = 0.5f * (z1.x + z2.x), Ai_ = 0.5f * (z1.y - z2.y);
        float Br_ = 0.5f * (z1.y + z2.y), Bi_ = 0.5f * (z2.x - z1.x);
        float wbr = cs * Br_ - sn * Bi_, wbi = cs * Bi_ + sn * Br_;
        float K1r = Ar_ + wbr, K1i = Ai_ + wbi;
        float K2r = Ar_ - wbr, K2i = -(Ai_ - wbi);
        if (j == 0) {
            __half2 v = __floats2half2_rn(K1r, K2r);
            P0[0] = v; if (dup) P1[0] = v;
        } else {
            __half2 v1 = __floats2half2_rn(K1r, K1i);
            P0[j] = v1; if (dup) P1[j] = v1;
            if (j != 4096) {
                __half2 v2 = __floats2half2_rn(K2r, K2i);
                P0[M - j] = v2; if (dup) P1[M - j] = v2;
            }
        }
        float cn = cs * cRo - sn * sRo; sn = sn * cRo + cs * sRo; cs = cn;
    }
}

// ---------------- conv: block (d,b): y = irfft(rfft(x)*(K + bias_d))[:8192] ------
// bias fold: y + x*bias_d == irfft(U_f * (K_f + bias_d))[:8192] (bias*delta0 has a
// flat real spectrum; irfft(rfft(x,2L),2L)[:L]==x exactly for zero-padded x).
// K row = kbase + (b*kstride + d)*SEQ; kstride=0 in workspace (shared-K) mode.
__global__ __launch_bounds__(512, 4) void conv_kernel(
    const float* __restrict__ x, const float* __restrict__ bias,
    float* outk, const float* __restrict__ kbase, int kstride)
{
    __shared__ float2 A[LDS_SZ];
    int t = threadIdx.x, d = blockIdx.x, b = blockIdx.y;
    const float* xp = x + ((size_t)(b * D_MODEL + d)) * SEQ;
    float bd = bias[d];

#pragma unroll
    for (int idx = 0; idx < 8; ++idx) {
        int n = t + (idx << 9);
        A[IDX(n)] = ((const float2*)xp)[n];
    }
    for (int n = 4096 + t; n < M; n += 512) A[IDX(n)] = make_float2(0.f, 0.f);
    __syncthreads();
    fft_fwd(A, t);

    const __half2* P = (const __half2*)(kbase + (size_t)(b * kstride + d) * SEQ);
    float cs, sn;
    __sincosf(-PI_F * (float)t * (1.0f / 8192.0f), &sn, &cs);
    const float cRo = 0.9807852804f, sRo = -0.1950903220f;   // exp(-i*pi/16)
    for (int j = t; j <= 4096; j += 512) {
        int jm = (M - j) & (M - 1);
        int p0 = rev13(j), p1 = rev13(jm);
        int q0 = IDX(p0), q1 = IDX(p1);
        float2 z1 = A[q0], z2 = A[q1];
        float Ar_ = 0.5f * (z1.x + z2.x), Ai_ = 0.5f * (z1.y - z2.y);
        float Br_ = 0.5f * (z1.y + z2.y), Bi_ = 0.5f * (z2.x - z1.x);
        float wbr = cs * Br_ - sn * Bi_, wbi = cs * Bi_ + sn * Br_;
        float U1r = Ar_ + wbr, U1i = Ai_ + wbi;
        float U2r = Ar_ - wbr, U2i = -(Ai_ - wbi);
        float K1r, K1i, K2r, K2i;
        if (j == 0) {
            __half2 v = P[0];
            K1r = __low2float(v) + bd;  K1i = 0.f;
            K2r = __high2float(v) + bd; K2i = 0.f;
        } else {
            __half2 v1 = P[j];
            __half2 v2 = P[M - j];
            K1r = __low2float(v1) + bd; K1i = __high2float(v1);
            K2r = __low2float(v2) + bd; K2i = __high2float(v2);
        }
        float P1r = U1r * K1r - U1i * K1i, P1i = U1r * K1i + U1i * K1r;
        float P2r = U2r * K2r - U2i * K2i, P2i = U2r * K2i + U2i * K2r;
        float Er = 0.5f * (P1r + P2r), Ei = 0.5f * (P1i - P2i);
        float Or = 0.5f * (P1r - P2r), Oi = 0.5f * (P1i + P2i);
        float G = cs * Oi - sn * Or;
        float H = cs * Or + sn * Oi;
        A[q0] = make_float2(Er - G, Ei + H);
        if (j != 0) A[q1] = make_float2(Er + G, -Ei + H);
        float cn = cs * cRo - sn * sRo; sn = sn * cRo + cs * sRo; cs = cn;
    }
    __syncthreads();
    fft_inv(A, t);

    const float invM = 1.0f / 8192.0f;
    float* op = outk + ((size_t)(b * D_MODEL + d)) * SEQ;
#pragma unroll
    for (int idx = 0; idx < 8; ++idx) {
        int n = t + (idx << 9);
        float2 v = A[IDX(n)];
        float2 ov;
        ov.x = v.x * invM;
        ov.y = v.y * invM;
        ((float2*)op)[n] = ov;
    }
}

extern "C" void kernel_launch(void* const* d_in, const int* in_sizes, int n_in,
                              void* d_out, int out_size, void* d_ws, size_t ws_size,
                              hipStream_t stream)
{
    (void)in_sizes; (void)n_in; (void)out_size;
    const float* x      = (const float*)d_in[0];
    // d_in[1] = L (always 8192, hardcoded)
    const float* z      = (const float*)d_in[2];
    const float* tvec   = (const float*)d_in[3];
    const float* freq   = (const float*)d_in[4];
    const float* W1     = (const float*)d_in[5];
    const float* b1     = (const float*)d_in[6];
    const float* W2     = (const float*)d_in[7];
    const float* b2     = (const float*)d_in[8];
    const float* W3     = (const float*)d_in[9];
    const float* b3     = (const float*)d_in[10];
    const float* Wout   = (const float*)d_in[11];
    const float* deltas = (const float*)d_in[12];
    const float* bias   = (const float*)d_in[13];
    float* out = (float*)d_out;

    // staging inside d_out (12,582,912 floats):
    //   h3T (64 x 8192, transposed) -> last 64 rows of b=1 half (dead after filt)
    //   k  -> rows (0,d)   (consumed by kf block d)
    //   K packed fp16: in workspace (single copy, shared by both batches) when
    //   ws_size permits; else duplicated into rows (0,d) and (1,d) of d_out.
    float* h3T = out + ((size_t)(2 * D_MODEL - 64) * SEQ);
    float* k   = out;

    const size_t kbytes = (size_t)D_MODEL * SEQ * sizeof(float);  // 25.2 MB packed K
    bool usews = (d_ws != nullptr) && (ws_size >= kbytes);
    float* kws = (float*)d_ws;
    float* kb0 = usews ? kws : out;
    float* kb1 = usews ? kws : out + (size_t)D_MODEL * SEQ;
    const float* kbase = usews ? kws : out;
    int kstride = usews ? 0 : D_MODEL;

    hipLaunchKernelGGL(mlp_kernel, dim3(SEQ / 32), dim3(256), 0, stream,
                       z, freq, W1, b1, W2, b2, W3, b3, h3T);
    hipLaunchKernelGGL(filt_kernel, dim3(SEQ / 128, D_MODEL / 64), dim3(256), 0, stream,
                       h3T, Wout, tvec, deltas, k);
    hipLaunchKernelGGL(kf_kernel, dim3(D_MODEL), dim3(512), 0, stream,
                       out, kb0, kb1);
    hipLaunchKernelGGL(conv_kernel, dim3(D_MODEL, BATCH), dim3(512), 0, stream,
                       x, bias, out, kbase, kstride);
}